// Round 10
// baseline (264.626 us; speedup 1.0000x reference)
//
#include <hip/hip_runtime.h>
#include <hip/hip_bf16.h>
#include <cstdint>

// ---------------------------------------------------------------------------
// Hamilton_V5  R19 = R18 with the A3 K-loop inner mechanics fixed:
//  - operands load DIRECTLY into intx8 halves (R18's shufflevector cost
//    ~123K VALU cy/CU of v_movs on the load->mfma dependency path:
//    VALUBusy 41%).
//  - depth-3 software pipeline, fully unrolled (16 steps, named sets
//    s0/s1/s2 -- static indexing per rule #20): each set's loads issued
//    ~3 mfma-sets (~250cy) ahead, covering L1/L2 latency (R18's even/odd
//    gave only ~140cy).
//  - registers: 3x32 sets + 64 AGPR acc + misc ~= 190 < 256 (no spill;
//    R18 verified 88 VGPR + 64 AGPR fits).
//  - Everything else byte-identical to R18 (fragment producers, hbwd,
//    L0/L1/L2, grids, swizzles).
// ---------------------------------------------------------------------------

typedef __bf16 bf16_t;
typedef __bf16 bf16x4_t __attribute__((ext_vector_type(4)));
typedef __bf16 bf16x8_t __attribute__((ext_vector_type(8)));
typedef float f32x4_t __attribute__((ext_vector_type(4)));
typedef float f32x16_t __attribute__((ext_vector_type(16)));
typedef int intx4_t __attribute__((ext_vector_type(4)));
typedef int intx8_t __attribute__((ext_vector_type(8)));

#define DIMD 128
#define NROW 4096
#define SMEM_G64 24576     // gemm64 3-buf (3*4096*2) ; aw3t 16896 fits
#define SMEM3_BYTES 24576  // hbwd 3-buf only; a3 uses no LDS

// branchless tanh: t=2^(2x*log2e); tanh=1-2/(t+1).
__device__ __forceinline__ float fast_tanh(float x) {
  float t = __builtin_amdgcn_exp2f(x * 2.8853900817779268f);
  return 1.f - 2.f * __builtin_amdgcn_rcpf(t + 1.f);
}

// f32 -> fp8 e4m3 (OCP), RNE+sat via HW cvt
__device__ __forceinline__ uint8_t to_fp8(float x) {
  return (uint8_t)(__builtin_amdgcn_cvt_pk_fp8_f32(x, x, 0, false) & 0xff);
}

// pack 4 f32 -> 4 fp8 bytes (byte0=a .. byte3=d) via 2 HW cvt_pk
__device__ __forceinline__ uint32_t pk4_fp8(float a, float b, float c,
                                            float d) {
  uint32_t lo = (uint32_t)__builtin_amdgcn_cvt_pk_fp8_f32(a, b, 0, false);
  return (uint32_t)__builtin_amdgcn_cvt_pk_fp8_f32(c, d, lo, true);
}

// async global->LDS, 16B per lane; LDS dest = wave-uniform base + lane*16
__device__ __forceinline__ void g2l16(const void* gp, void* lp) {
  __builtin_amdgcn_global_load_lds(
      reinterpret_cast<__attribute__((address_space(1))) void*>(
          reinterpret_cast<uintptr_t>(gp)),
      reinterpret_cast<__attribute__((address_space(3))) void*>(
          reinterpret_cast<uintptr_t>(lp)),
      16, 0, 0);
}

// DPP accumulating add (VALU pipe -- no LDS). bound_ctrl=1 => 0-fill.
template <int CTRL>
__device__ __forceinline__ float dpp_addf(float v) {
  return v + __int_as_float(__builtin_amdgcn_update_dpp(
                 0, __float_as_int(v), CTRL, 0xf, 0xf, true));
}
// sum over each 32-lane half; result in lane 31 (half 0) / lane 63 (half 1).
__device__ __forceinline__ float dpp_sum32(float v) {
  v = dpp_addf<0x111>(v);  // row_shr:1
  v = dpp_addf<0x112>(v);  // row_shr:2
  v = dpp_addf<0x114>(v);  // row_shr:4
  v = dpp_addf<0x118>(v);  // row_shr:8  -> lane15/31/47/63 = row sums
  v = dpp_addf<0x142>(v);  // row_bcast15 -> lane31/63 = 32-lane sums
  return v;
}

// ---------------------------------------------------------------------------
// bf16 GEMM, 64x64 tile, BK=32, 4 waves 2x2 (each 32x32 = 2x2 mfma 16x16x32).
// Triple-buffered LDS, depth-2 prefetch, counted vmcnt(2) per step.
// EPI 0: bf16 tanh(C+b); EPI 4: fp8 x64 fragment-major (h2F).
// ---------------------------------------------------------------------------
template <int EPI>
__device__ __forceinline__ void gemm64_body(char* smem, int bx, int by,
                                            const bf16_t* A, int lda,
                                            const bf16_t* B, int ldb, int K,
                                            const float* bias, void* outp,
                                            int ldo) {
  constexpr int BK = 32;
  bf16_t* As = (bf16_t*)smem;   // 3 x 64*32
  bf16_t* Bs = As + 3 * 2048;   // 3 x 64*32
  const int NT = K / BK;

  const int m0 = bx * 64;
  const int n0 = by * 64;
  const int tid = threadIdx.x;
  const int wave = tid >> 6;
  const int lane = tid & 63;
  const int wm = wave >> 1;
  const int wn = wave & 1;

  const int sr = lane >> 2;
  const int sk = (((lane & 3) ^ ((sr >> 1) & 3)) * 8);
  const int fr = lane & 15;
  const int fk = (((lane >> 4) ^ ((fr >> 1) & 3)) * 8);
  const int rb = wave * 16;  // each wave stages 16 rows of A and B

  const bf16_t* Ag = A + (size_t)(m0 + rb + sr) * lda + sk;
  const bf16_t* Bg = B + (size_t)(n0 + rb + sr) * ldb + sk;

#define G64_STAGE(buf, k0)                              \
  do {                                                  \
    g2l16(Ag + (k0), As + (buf) * 2048 + rb * BK);      \
    g2l16(Bg + (k0), Bs + (buf) * 2048 + rb * BK);      \
  } while (0)

  f32x4_t acc[2][2] = {};

  G64_STAGE(0, 0);
  G64_STAGE(1, BK);
  asm volatile("s_waitcnt vmcnt(2)" ::: "memory");
  __builtin_amdgcn_s_barrier();
  asm volatile("" ::: "memory");

  for (int t = 0; t < NT; ++t) {
    if (t + 2 < NT) G64_STAGE((t + 2) % 3, (t + 2) * BK);
    const bf16_t* Ab = As + (t % 3) * 2048;
    const bf16_t* Bb = Bs + (t % 3) * 2048;

    bf16x8_t af[2], bb[2];
#pragma unroll
    for (int u = 0; u < 2; ++u) {
      af[u] = *(const bf16x8_t*)(Ab + (wm * 32 + u * 16 + fr) * BK + fk);
      bb[u] = *(const bf16x8_t*)(Bb + (wn * 32 + u * 16 + fr) * BK + fk);
    }
#pragma unroll
    for (int i = 0; i < 2; ++i)
#pragma unroll
      for (int j = 0; j < 2; ++j)
        acc[i][j] = __builtin_amdgcn_mfma_f32_16x16x32_bf16(af[i], bb[j],
                                                            acc[i][j], 0, 0, 0);
    if (t < NT - 1) {
      if (t + 2 < NT)
        asm volatile("s_waitcnt vmcnt(2)" ::: "memory");
      else
        asm volatile("s_waitcnt vmcnt(0)" ::: "memory");
      __builtin_amdgcn_s_barrier();
      asm volatile("" ::: "memory");
    }
  }
#undef G64_STAGE

  // C/D layout (m89): col = lane&15, row = (lane>>4)*4 + reg
#pragma unroll
  for (int i = 0; i < 2; ++i) {
    const int row = m0 + wm * 32 + i * 16 + (lane >> 4) * 4;
#pragma unroll
    for (int j = 0; j < 2; ++j) {
      const int col = n0 + wn * 32 + j * 16 + fr;
      if constexpr (EPI == 0) {
        bf16_t* O = (bf16_t*)outp;
        const float b = bias[col];
#pragma unroll
        for (int r = 0; r < 4; ++r)
          O[(size_t)(row + r) * ldo + col] = (bf16_t)fast_tanh(acc[i][j][r] + b);
      } else {  // EPI 4: h2 fragment-major fp8
        uint8_t* O = (uint8_t*)outp;
        const float b = bias[col];
        const int kb = col >> 6;
        const int khalf = (col >> 5) & 1;
        const int kin = col & 31;
#pragma unroll
        for (int r = 0; r < 4; ++r) {
          const int rw = row + r;
          O[(size_t)((rw >> 5) * 16 + kb) * 2048 +
            (khalf * 32 + (rw & 31)) * 32 + kin] =
              to_fp8(64.f * fast_tanh(acc[i][j][r] + b));
        }
      }
    }
  }
}

// ---------------------------------------------------------------------------
// Hbwd bf16 GEMM for 512-thread launch: 64x64 tile, BK=32, 8 waves arranged
// 2x4; per-wave 32x16 = 2x1 mfma 16x16x32.  dx store / dv atomicAdd(-C).
// Triple-buffer/counted-vmcnt pipeline (1 stage op per wave).
// ---------------------------------------------------------------------------
__device__ __forceinline__ void hbwd64_body(char* smem, int bx, int by,
                                            const bf16_t* A, int lda,
                                            const bf16_t* B, int ldb, int K,
                                            float* out, int ldo) {
  constexpr int BK = 32;
  bf16_t* As = (bf16_t*)smem;  // 3 x 64*32
  bf16_t* Bs = As + 3 * 2048;
  const int NT = K / BK;  // 20

  const int m0 = bx * 64;
  const int n0 = by * 64;
  const int tid = threadIdx.x;
  const int wave = tid >> 6;  // 0..7
  const int lane = tid & 63;
  const int wm = wave >> 2;   // 0..1
  const int wn = wave & 3;    // 0..3

  const int sr = lane >> 2;
  const int sk = (((lane & 3) ^ ((sr >> 1) & 3)) * 8);
  const int fr = lane & 15;
  const int fk = (((lane >> 4) ^ ((fr >> 1) & 3)) * 8);

  // waves 0..3 stage A rows, 4..7 stage B rows (1 g2l16 per wave per step)
  const int rbs = (wave & 3) * 16;
  const bf16_t* Sg = (wave < 4) ? A + (size_t)(m0 + rbs + sr) * lda + sk
                                : B + (size_t)(n0 + rbs + sr) * ldb + sk;
  bf16_t* Sl = ((wave < 4) ? As : Bs) + rbs * BK;

  f32x4_t acc[2] = {};

  g2l16(Sg, Sl);
  g2l16(Sg + BK, Sl + 2048);
  asm volatile("s_waitcnt vmcnt(1)" ::: "memory");
  __builtin_amdgcn_s_barrier();
  asm volatile("" ::: "memory");

  for (int t = 0; t < NT; ++t) {
    if (t + 2 < NT) g2l16(Sg + (t + 2) * BK, Sl + ((t + 2) % 3) * 2048);
    const bf16_t* Ab = As + (t % 3) * 2048;
    const bf16_t* Bb = Bs + (t % 3) * 2048;

    const bf16x8_t bb = *(const bf16x8_t*)(Bb + (wn * 16 + fr) * BK + fk);
#pragma unroll
    for (int u = 0; u < 2; ++u) {
      const bf16x8_t af =
          *(const bf16x8_t*)(Ab + (wm * 32 + u * 16 + fr) * BK + fk);
      acc[u] = __builtin_amdgcn_mfma_f32_16x16x32_bf16(af, bb, acc[u], 0, 0, 0);
    }
    if (t < NT - 1) {
      if (t + 2 < NT)
        asm volatile("s_waitcnt vmcnt(1)" ::: "memory");
      else
        asm volatile("s_waitcnt vmcnt(0)" ::: "memory");
      __builtin_amdgcn_s_barrier();
      asm volatile("" ::: "memory");
    }
  }

  // C/D layout (m89): col = lane&15, row = (lane>>4)*4 + reg
  const bool dx = (n0 < DIMD);
  const int col = n0 + wn * 16 + fr;
#pragma unroll
  for (int t = 0; t < 2; ++t) {
    const int row = m0 + wm * 32 + t * 16 + (lane >> 4) * 4;
#pragma unroll
    for (int r = 0; r < 4; ++r) {
      const size_t idx = (size_t)(row + r) * ldo + col;
      if (dx) out[idx] = acc[t][r];
      else atomicAdd(&out[idx], -acc[t][r]);  // dv_H shares with dvA
    }
  }
}

// ---------------------------------------------------------------------------
// A3 fused GEMM, MX-fp8, R19: 512 threads / 8 waves, BM=256, BN=128, BK=64.
// Wave grid 4x2: each wave 64x64 via 2x2 mfma 32x32x64 (acc[2][2] = 64 AGPR).
// NO LDS, NO BARRIERS: operands stream L2->reg as pre-swizzled fragments.
// Depth-3 pipeline, fully unrolled, named sets s0/s1/s2 loaded directly
// into intx8 halves (no shufflevector movs).
// ---------------------------------------------------------------------------
__device__ __forceinline__ void a3_body(int bx, int by, const uint8_t* AF,
                                        const uint8_t* BF, float* out,
                                        const float* ab3, const float* uvec) {
  const int tid = threadIdx.x;
  const int wave = tid >> 6;  // 0..7
  const int lane = tid & 63;
  const int wm = wave >> 1;   // 0..3 : 64-row strip
  const int wn = wave & 1;    // 0..1 : 64-col strip
  const int rl = lane & 31;
  const int m0 = bx * 256;
  const int n0 = by * 128;

  // fragment stream base pointers (lane's 32B slice of each 2KB chunk)
  const uint8_t* bp[4];
#pragma unroll
  for (int i = 0; i < 2; ++i)
    bp[i] = AF + (size_t)(bx * 8 + wm * 2 + i) * 16 * 2048 + lane * 32;
#pragma unroll
  for (int j = 0; j < 2; ++j)
    bp[2 + j] = BF + (size_t)(by * 4 + wn * 2 + j) * 16 * 2048 + lane * 32;

  f32x16_t acc[2][2] = {};
  intx8_t s0[4], s1[4], s2[4];

  // load k-block (koff) of all 4 streams straight into intx8 halves
#define A3_LD(S, koff)                                                       \
  _Pragma("unroll") for (int q = 0; q < 4; ++q) {                            \
    *(intx4_t*)&S[q] = *(const intx4_t*)(bp[q] + (koff)*2048);               \
    *((intx4_t*)&S[q] + 1) = *(const intx4_t*)(bp[q] + (koff)*2048 + 16);    \
  }

#define A3_MM(S)                                                             \
  acc[0][0] = __builtin_amdgcn_mfma_scale_f32_32x32x64_f8f6f4(               \
      S[0], S[2], acc[0][0], 0, 0, 0, 0x79797979, 0, 0x79797979);            \
  acc[0][1] = __builtin_amdgcn_mfma_scale_f32_32x32x64_f8f6f4(               \
      S[0], S[3], acc[0][1], 0, 0, 0, 0x79797979, 0, 0x79797979);            \
  acc[1][0] = __builtin_amdgcn_mfma_scale_f32_32x32x64_f8f6f4(               \
      S[1], S[2], acc[1][0], 0, 0, 0, 0x79797979, 0, 0x79797979);            \
  acc[1][1] = __builtin_amdgcn_mfma_scale_f32_32x32x64_f8f6f4(               \
      S[1], S[3], acc[1][1], 0, 0, 0, 0x79797979, 0, 0x79797979);

  A3_LD(s0, 0) A3_LD(s1, 1) A3_LD(s2, 2)
  A3_MM(s0) A3_LD(s0, 3)    // t=0
  A3_MM(s1) A3_LD(s1, 4)    // t=1
  A3_MM(s2) A3_LD(s2, 5)    // t=2
  A3_MM(s0) A3_LD(s0, 6)    // t=3
  A3_MM(s1) A3_LD(s1, 7)    // t=4
  A3_MM(s2) A3_LD(s2, 8)    // t=5
  A3_MM(s0) A3_LD(s0, 9)    // t=6
  A3_MM(s1) A3_LD(s1, 10)   // t=7
  A3_MM(s2) A3_LD(s2, 11)   // t=8
  A3_MM(s0) A3_LD(s0, 12)   // t=9
  A3_MM(s1) A3_LD(s1, 13)   // t=10
  A3_MM(s2) A3_LD(s2, 14)   // t=11
  A3_MM(s0) A3_LD(s0, 15)   // t=12
  A3_MM(s1)                 // t=13
  A3_MM(s2)                 // t=14
  A3_MM(s0)                 // t=15
#undef A3_LD
#undef A3_MM

  // epilogue: C/D col = lane&31, row = (reg&3)+8*(reg>>2)+4*(lane>>5).
  // block's 128 cols are one full u-period -> out column 128+by.
  const int q = lane >> 5;
  float uu[2], b3[2];
#pragma unroll
  for (int j = 0; j < 2; ++j) {
    uu[j] = uvec[wn * 64 + j * 32 + rl];
    b3[j] = ab3[n0 + wn * 64 + j * 32 + rl];
  }
  const int ocol = 128 + by;
#pragma unroll
  for (int i = 0; i < 2; ++i) {
    float s16[16];
#pragma unroll
    for (int r = 0; r < 16; ++r)
      s16[r] = fast_tanh(acc[i][0][r] + b3[0]) * uu[0] +
               fast_tanh(acc[i][1][r] + b3[1]) * uu[1];
#pragma unroll
    for (int r = 0; r < 16; ++r) s16[r] = dpp_sum32(s16[r]);
    if (rl == 31) {  // lanes 31 and 63 hold the two q-half sums
      const int rowb = m0 + wm * 64 + i * 32 + 4 * q;
#pragma unroll
      for (int r = 0; r < 16; ++r)
        atomicAdd(&out[(size_t)(rowb + (r & 3) + 8 * (r >> 2)) * 256 + ocol],
                  s16[r]);
    }
  }
}

// ---------------------------------------------------------------------------
// transposes / cvt helpers
// ---------------------------------------------------------------------------
__device__ __forceinline__ void tcvt_body(char* smem, const float* in,
                                          bf16_t* out, int R, int C, int bx,
                                          int by) {
  float(*t)[33] = (float(*)[33])smem;  // 4224 B
  const int c0 = bx * 32;
  const int r0 = by * 32;
  const int tx = threadIdx.x & 31;
  const int ty = threadIdx.x >> 5;
#pragma unroll
  for (int k = 0; k < 4; ++k)
    t[ty + k * 8][tx] = in[(size_t)(r0 + ty + k * 8) * C + c0 + tx];
  __syncthreads();
#pragma unroll
  for (int k = 0; k < 4; ++k)
    out[(size_t)(c0 + ty + k * 8) * R + r0 + tx] = (bf16_t)t[tx][ty + k * 8];
}

// Aw3 (1024 x 16384) -> fp8 x64, FRAGMENT-MAJOR (Aw3T8F).
// 128x128 tile per block (1024 blocks), float4 reads, cvt_pk packing,
// u32-transposed LDS [128][33]; drain writes fragment chunks:
//   chunk ((cb*16)+kb)*2048, byte (khalf*32 + col%32)*32 + k%32.
__device__ __forceinline__ void aw3t_body(char* smem, const float* Aw3,
                                          uint8_t* Aw3T8F, int b) {
  uint32_t(*T)[33] = (uint32_t(*)[33])smem;  // 16896 B
  const int ct = b & 127;
  const int rt = b >> 7;
  const size_t c0 = (size_t)ct * 128;
  const int r0 = rt * 128;
  const int tx = threadIdx.x & 31;  // col-chunk (4 f32)
  const int g = threadIdx.x >> 5;   // 0..7 row-group
#pragma unroll
  for (int k = 0; k < 4; ++k) {
    const int rr = r0 + 4 * g + 32 * k;
    const float4 v0 = *(const float4*)(Aw3 + (size_t)(rr + 0) * 16384 + c0 + 4 * tx);
    const float4 v1 = *(const float4*)(Aw3 + (size_t)(rr + 1) * 16384 + c0 + 4 * tx);
    const float4 v2 = *(const float4*)(Aw3 + (size_t)(rr + 2) * 16384 + c0 + 4 * tx);
    const float4 v3 = *(const float4*)(Aw3 + (size_t)(rr + 3) * 16384 + c0 + 4 * tx);
    const int r4 = g + 8 * k;  // row/4 within tile (k-dim of output)
    T[4 * tx + 0][r4] = pk4_fp8(64.f * v0.x, 64.f * v1.x, 64.f * v2.x, 64.f * v3.x);
    T[4 * tx + 1][r4] = pk4_fp8(64.f * v0.y, 64.f * v1.y, 64.f * v2.y, 64.f * v3.y);
    T[4 * tx + 2][r4] = pk4_fp8(64.f * v0.z, 64.f * v1.z, 64.f * v2.z, 64.f * v3.z);
    T[4 * tx + 3][r4] = pk4_fp8(64.f * v0.w, 64.f * v1.w, 64.f * v2.w, 64.f * v3.w);
  }
  __syncthreads();
  // T[cc][tx] = 4 fp8 bytes: col = c0+cc, k = r0+4*tx .. +3
  const int kb = (rt << 1) + (tx >> 4);     // k-block (64)
  const int khalf = (tx >> 3) & 1;          // k-half (32)
  const int kin = (tx & 7) << 2;            // k%32 (4-aligned)
#pragma unroll
  for (int k2 = 0; k2 < 16; ++k2) {
    const int cc = g + 8 * k2;
    const int cb = (ct << 2) + (cc >> 5);
    const int cin = cc & 31;
    *(uint32_t*)(Aw3T8F + (size_t)(cb * 16 + kb) * 2048 +
                 (khalf * 32 + cin) * 32 + kin) = T[cc][tx];
  }
}

// one wave handles one row: pre2 = h.Hw2; w_j = s*Hw2_j*(1-h_j^2)
__device__ __forceinline__ void hgrad_row(int row, const bf16_t* h,
                                          const float* Hw2, const float* Hb2,
                                          bf16_t* wout) {
  const int lane = threadIdx.x & 63;
  float hv[10], wv[10];
  float pre2 = 0.f;
#pragma unroll
  for (int t = 0; t < 10; ++t) {
    const int j = lane + t * 64;
    hv[t] = (float)h[(size_t)row * 640 + j];
    wv[t] = Hw2[j];
    pre2 += hv[t] * wv[t];
  }
#pragma unroll
  for (int d = 1; d < 64; d <<= 1) pre2 += __shfl_xor(pre2, d, 64);
  const float y = fast_tanh(pre2 + Hb2[0]);
  const float s = 1.f - y * y;
#pragma unroll
  for (int t = 0; t < 10; ++t) {
    const int j = lane + t * 64;
    wout[(size_t)row * 640 + j] = (bf16_t)(s * wv[t] * (1.f - hv[t] * hv[t]));
  }
}

// ---------------------------------------------------------------------------
// L0: inp cvt (1024) + Hw1T (160) + Aw1T (64) + Aw2T (512) + Hw1_bf cvt (160)
//     + zero-out (1024) = 2944 blocks
// ---------------------------------------------------------------------------
__global__ __launch_bounds__(256) void launch0(
    const float* __restrict__ inp, bf16_t* __restrict__ inp_bf,
    const float* __restrict__ Hw1, bf16_t* __restrict__ Hw1T,
    bf16_t* __restrict__ Hw1_bf, const float* __restrict__ Aw1,
    bf16_t* __restrict__ Aw1T, const float* __restrict__ Aw2,
    bf16_t* __restrict__ Aw2T, float* __restrict__ out) {
  __shared__ __align__(16) char smem[4224];
  int b = blockIdx.x;
  if (b < 1024) {
    const int i = b * 256 + threadIdx.x;
    const float4 v = ((const float4*)inp)[i];
    bf16x4_t o = {(bf16_t)v.x, (bf16_t)v.y, (bf16_t)v.z, (bf16_t)v.w};
    ((bf16x4_t*)inp_bf)[i] = o;
  } else if (b < 1184) {
    int s = b - 1024;
    tcvt_body(smem, Hw1, Hw1T, 256, 640, s % 20, s / 20);
  } else if (b < 1248) {
    int s = b - 1184;
    tcvt_body(smem, Aw1, Aw1T, 128, 512, s % 16, s / 16);
  } else if (b < 1760) {
    int s = b - 1248;
    tcvt_body(smem, Aw2, Aw2T, 512, 1024, s % 32, s / 32);
  } else if (b < 1920) {
    const int i = (b - 1760) * 256 + threadIdx.x;
    const float4 v = ((const float4*)Hw1)[i];
    bf16x4_t o = {(bf16_t)v.x, (bf16_t)v.y, (bf16_t)v.z, (bf16_t)v.w};
    ((bf16x4_t*)Hw1_bf)[i] = o;
  } else {
    const int i = (b - 1920) * 256 + threadIdx.x;
    ((float4*)out)[i] = make_float4(0.f, 0.f, 0.f, 0.f);
  }
}

// ---------------------------------------------------------------------------
// L1: Hfwd 64^2 (640) + A1 64^2 (512) + Aw3T tiles [0,512) = 1664 blocks
// ---------------------------------------------------------------------------
__global__ __launch_bounds__(256) void launch1(
    const bf16_t* __restrict__ inp_bf, const bf16_t* __restrict__ Hw1T,
    const float* __restrict__ Hb1, bf16_t* __restrict__ h_bf,
    const bf16_t* __restrict__ Aw1T, const float* __restrict__ Ab1,
    bf16_t* __restrict__ h1_bf, const float* __restrict__ Aw3,
    uint8_t* __restrict__ Aw3T8F) {
  __shared__ __align__(16) char smem[SMEM_G64];
  const int b = blockIdx.x;
  if (b < 640) {
    gemm64_body<0>(smem, b % 64, b / 64, inp_bf, 256, Hw1T, 256, 256, Hb1,
                   h_bf, 640);
  } else if (b < 1152) {
    const int i = b - 640;
    gemm64_body<0>(smem, i % 64, i / 64, inp_bf, 256, Aw1T, 128, 128, Ab1,
                   h1_bf, 512);
  } else {
    aw3t_body(smem, Aw3, Aw3T8F, b - 1152);  // tiles 0..511
  }
}

// ---------------------------------------------------------------------------
// L2: A2->h2F 64^2 (1024) + hgrad (1024) + Aw3T tiles [512,1024) = 2560
// ---------------------------------------------------------------------------
__global__ __launch_bounds__(256) void launch2(
    const bf16_t* __restrict__ h1_bf, const bf16_t* __restrict__ Aw2T,
    const float* __restrict__ Ab2, uint8_t* __restrict__ h2F,
    const bf16_t* __restrict__ h_bf, const float* __restrict__ Hw2,
    const float* __restrict__ Hb2, bf16_t* __restrict__ w_bf,
    const float* __restrict__ Aw3, uint8_t* __restrict__ Aw3T8F) {
  __shared__ __align__(16) char smem[SMEM_G64];
  const int b = blockIdx.x;
  if (b < 1024) {
    gemm64_body<4>(smem, b % 64, b / 64, h1_bf, 512, Aw2T, 512, 512, Ab2,
                   h2F, 0);
  } else if (b < 2048) {
    const int row = (b - 1024) * 4 + (threadIdx.x >> 6);
    hgrad_row(row, h_bf, Hw2, Hb2, w_bf);
  } else {
    aw3t_body(smem, Aw3, Aw3T8F, 512 + (b - 2048));  // tiles 512..1023
  }
}

// ---------------------------------------------------------------------------
// L3 (512 threads): Hbwd 64^2 8-wave (256) + A3 no-LDS (2048) = 2304.
// A3 swizzle: hardware XCD = p%8; each XCD owns 16 contiguous by values
// (B working set 16 x 128KB = 2MB -> L2-resident), bx varies slowest.
// ---------------------------------------------------------------------------
__global__ __launch_bounds__(512, 2) void launch3(
    const bf16_t* __restrict__ w_bf, const bf16_t* __restrict__ Hw1_bf,
    float* __restrict__ out, const uint8_t* __restrict__ h2F,
    const uint8_t* __restrict__ Aw3T8F, const float* __restrict__ Ab3,
    const float* __restrict__ uvec) {
  __shared__ __align__(16) char smem[SMEM3_BYTES];
  const int b = blockIdx.x;
  if (b < 256) {
    hbwd64_body(smem, b % 64, b / 64, w_bf, 640, Hw1_bf, 640, 640, out, 256);
  } else {
    const int p = b - 256;                          // 0..2047; hw XCD = p % 8
    const int by = (p & 7) * 16 + ((p >> 3) & 15);  // 0..127
    const int bx = p >> 7;                          // 0..15
    a3_body(bx, by, h2F, Aw3T8F, out, Ab3, uvec);
  }
}

// ---------------------------------------------------------------------------
extern "C" void kernel_launch(void* const* d_in, const int* in_sizes, int n_in,
                              void* d_out, int out_size, void* d_ws,
                              size_t ws_size, hipStream_t stream) {
  (void)in_sizes; (void)n_in; (void)out_size; (void)ws_size;
  const float* inp = (const float*)d_in[1];
  const float* Hw1 = (const float*)d_in[2];
  const float* Hb1 = (const float*)d_in[3];
  const float* Hw2 = (const float*)d_in[4];
  const float* Hb2 = (const float*)d_in[5];
  const float* Aw1 = (const float*)d_in[6];
  const float* Ab1 = (const float*)d_in[7];
  const float* Aw2 = (const float*)d_in[8];
  const float* Ab2 = (const float*)d_in[9];
  const float* Aw3 = (const float*)d_in[10];
  const float* Ab3 = (const float*)d_in[11];
  const float* u = (const float*)d_in[12];
  float* out = (float*)d_out;

  char* ws = (char*)d_ws;
  bf16_t* inp_bf = (bf16_t*)ws;    ws += (size_t)NROW * 256 * 2;
  bf16_t* Hw1_bf = (bf16_t*)ws;    ws += (size_t)256 * 640 * 2;
  bf16_t* Hw1T = (bf16_t*)ws;      ws += (size_t)640 * 256 * 2;
  bf16_t* Aw1T = (bf16_t*)ws;      ws += (size_t)512 * 128 * 2;
  bf16_t* Aw2T = (bf16_t*)ws;      ws += (size_t)1024 * 512 * 2;
  uint8_t* Aw3T8F = (uint8_t*)ws;  ws += (size_t)16384 * 1024;
  bf16_t* h_bf = (bf16_t*)ws;      ws += (size_t)NROW * 640 * 2;
  bf16_t* w_bf = (bf16_t*)ws;      ws += (size_t)NROW * 640 * 2;
  bf16_t* h1_bf = (bf16_t*)ws;     ws += (size_t)NROW * 512 * 2;
  uint8_t* h2F = (uint8_t*)ws;     ws += (size_t)NROW * 1024;

  launch0<<<2944, 256, 0, stream>>>(inp, inp_bf, Hw1, Hw1T, Hw1_bf, Aw1, Aw1T,
                                    Aw2, Aw2T, out);
  launch1<<<1664, 256, 0, stream>>>(inp_bf, Hw1T, Hb1, h_bf, Aw1T, Ab1, h1_bf,
                                    Aw3, Aw3T8F);
  launch2<<<2560, 256, 0, stream>>>(h1_bf, Aw2T, Ab2, h2F, h_bf, Hw2, Hb2,
                                    w_bf, Aw3, Aw3T8F);
  launch3<<<2304, 512, 0, stream>>>(w_bf, Hw1_bf, out, h2F, Aw3T8F, Ab3, u);
}

// Round 11
// 240.640 us; speedup vs baseline: 1.0997x; 1.0997x over previous
//
#include <hip/hip_runtime.h>
#include <hip/hip_bf16.h>
#include <cstdint>

// ---------------------------------------------------------------------------
// Hamilton_V5  R20 = R19 with A3 occupancy un-stranded:
//  - R19 diagnosis: 8-wave blocks + 132 reg/wave demand -> only 1 block/CU
//    (8 of 12 possible waves; OccupancyPercent 23%). The barrier-free A3
//    K-loop relies on TLP to hide L2 latency -- block granularity wasted it.
//  - launch3 now 256-thread (4-wave) blocks: a3 tile 128x128 (wave grid
//    2x2, per-wave 64x64 unchanged), grid 32x128 = 4096 + 256 hbwd blocks.
//    __launch_bounds__(256,3) -> 3 blocks/CU = 12 waves (37.5%).
//  - hbwd reverts to the 4-wave gemm64_body path (EPI 1, R9 epilogue).
//  - K-loop mechanics identical to R19 (fragment-direct, depth-3 unrolled,
//    direct intx8-half loads). Producers/L0/L1/L2 byte-identical.
// ---------------------------------------------------------------------------

typedef __bf16 bf16_t;
typedef __bf16 bf16x4_t __attribute__((ext_vector_type(4)));
typedef __bf16 bf16x8_t __attribute__((ext_vector_type(8)));
typedef float f32x4_t __attribute__((ext_vector_type(4)));
typedef float f32x16_t __attribute__((ext_vector_type(16)));
typedef int intx4_t __attribute__((ext_vector_type(4)));
typedef int intx8_t __attribute__((ext_vector_type(8)));

#define DIMD 128
#define NROW 4096
#define SMEM_G64 24576     // gemm64 3-buf (3*4096*2) ; aw3t 16896 fits
#define SMEM3_BYTES 24576  // hbwd 3-buf only; a3 uses no LDS

// branchless tanh: t=2^(2x*log2e); tanh=1-2/(t+1).
__device__ __forceinline__ float fast_tanh(float x) {
  float t = __builtin_amdgcn_exp2f(x * 2.8853900817779268f);
  return 1.f - 2.f * __builtin_amdgcn_rcpf(t + 1.f);
}

// f32 -> fp8 e4m3 (OCP), RNE+sat via HW cvt
__device__ __forceinline__ uint8_t to_fp8(float x) {
  return (uint8_t)(__builtin_amdgcn_cvt_pk_fp8_f32(x, x, 0, false) & 0xff);
}

// pack 4 f32 -> 4 fp8 bytes (byte0=a .. byte3=d) via 2 HW cvt_pk
__device__ __forceinline__ uint32_t pk4_fp8(float a, float b, float c,
                                            float d) {
  uint32_t lo = (uint32_t)__builtin_amdgcn_cvt_pk_fp8_f32(a, b, 0, false);
  return (uint32_t)__builtin_amdgcn_cvt_pk_fp8_f32(c, d, lo, true);
}

// async global->LDS, 16B per lane; LDS dest = wave-uniform base + lane*16
__device__ __forceinline__ void g2l16(const void* gp, void* lp) {
  __builtin_amdgcn_global_load_lds(
      reinterpret_cast<__attribute__((address_space(1))) void*>(
          reinterpret_cast<uintptr_t>(gp)),
      reinterpret_cast<__attribute__((address_space(3))) void*>(
          reinterpret_cast<uintptr_t>(lp)),
      16, 0, 0);
}

// DPP accumulating add (VALU pipe -- no LDS). bound_ctrl=1 => 0-fill.
template <int CTRL>
__device__ __forceinline__ float dpp_addf(float v) {
  return v + __int_as_float(__builtin_amdgcn_update_dpp(
                 0, __float_as_int(v), CTRL, 0xf, 0xf, true));
}
// sum over each 32-lane half; result in lane 31 (half 0) / lane 63 (half 1).
__device__ __forceinline__ float dpp_sum32(float v) {
  v = dpp_addf<0x111>(v);  // row_shr:1
  v = dpp_addf<0x112>(v);  // row_shr:2
  v = dpp_addf<0x114>(v);  // row_shr:4
  v = dpp_addf<0x118>(v);  // row_shr:8  -> lane15/31/47/63 = row sums
  v = dpp_addf<0x142>(v);  // row_bcast15 -> lane31/63 = 32-lane sums
  return v;
}

// ---------------------------------------------------------------------------
// bf16 GEMM, 64x64 tile, BK=32, 4 waves 2x2 (each 32x32 = 2x2 mfma 16x16x32).
// Triple-buffered LDS, depth-2 prefetch, counted vmcnt(2) per step.
// EPI 0: bf16 tanh(C+b); EPI 1: dx store / dv atomicAdd(-C);
// EPI 4: fp8 x64 fragment-major (h2F).  (256-thread launches.)
// ---------------------------------------------------------------------------
template <int EPI>
__device__ __forceinline__ void gemm64_body(char* smem, int bx, int by,
                                            const bf16_t* A, int lda,
                                            const bf16_t* B, int ldb, int K,
                                            const float* bias, void* outp,
                                            int ldo) {
  constexpr int BK = 32;
  bf16_t* As = (bf16_t*)smem;   // 3 x 64*32
  bf16_t* Bs = As + 3 * 2048;   // 3 x 64*32
  const int NT = K / BK;

  const int m0 = bx * 64;
  const int n0 = by * 64;
  const int tid = threadIdx.x;
  const int wave = tid >> 6;
  const int lane = tid & 63;
  const int wm = wave >> 1;
  const int wn = wave & 1;

  const int sr = lane >> 2;
  const int sk = (((lane & 3) ^ ((sr >> 1) & 3)) * 8);
  const int fr = lane & 15;
  const int fk = (((lane >> 4) ^ ((fr >> 1) & 3)) * 8);
  const int rb = wave * 16;  // each wave stages 16 rows of A and B

  const bf16_t* Ag = A + (size_t)(m0 + rb + sr) * lda + sk;
  const bf16_t* Bg = B + (size_t)(n0 + rb + sr) * ldb + sk;

#define G64_STAGE(buf, k0)                              \
  do {                                                  \
    g2l16(Ag + (k0), As + (buf) * 2048 + rb * BK);      \
    g2l16(Bg + (k0), Bs + (buf) * 2048 + rb * BK);      \
  } while (0)

  f32x4_t acc[2][2] = {};

  G64_STAGE(0, 0);
  G64_STAGE(1, BK);
  asm volatile("s_waitcnt vmcnt(2)" ::: "memory");
  __builtin_amdgcn_s_barrier();
  asm volatile("" ::: "memory");

  for (int t = 0; t < NT; ++t) {
    if (t + 2 < NT) G64_STAGE((t + 2) % 3, (t + 2) * BK);
    const bf16_t* Ab = As + (t % 3) * 2048;
    const bf16_t* Bb = Bs + (t % 3) * 2048;

    bf16x8_t af[2], bb[2];
#pragma unroll
    for (int u = 0; u < 2; ++u) {
      af[u] = *(const bf16x8_t*)(Ab + (wm * 32 + u * 16 + fr) * BK + fk);
      bb[u] = *(const bf16x8_t*)(Bb + (wn * 32 + u * 16 + fr) * BK + fk);
    }
#pragma unroll
    for (int i = 0; i < 2; ++i)
#pragma unroll
      for (int j = 0; j < 2; ++j)
        acc[i][j] = __builtin_amdgcn_mfma_f32_16x16x32_bf16(af[i], bb[j],
                                                            acc[i][j], 0, 0, 0);
    if (t < NT - 1) {
      if (t + 2 < NT)
        asm volatile("s_waitcnt vmcnt(2)" ::: "memory");
      else
        asm volatile("s_waitcnt vmcnt(0)" ::: "memory");
      __builtin_amdgcn_s_barrier();
      asm volatile("" ::: "memory");
    }
  }
#undef G64_STAGE

  // C/D layout (m89): col = lane&15, row = (lane>>4)*4 + reg
#pragma unroll
  for (int i = 0; i < 2; ++i) {
    const int row = m0 + wm * 32 + i * 16 + (lane >> 4) * 4;
#pragma unroll
    for (int j = 0; j < 2; ++j) {
      const int col = n0 + wn * 32 + j * 16 + fr;
      if constexpr (EPI == 0) {
        bf16_t* O = (bf16_t*)outp;
        const float b = bias[col];
#pragma unroll
        for (int r = 0; r < 4; ++r)
          O[(size_t)(row + r) * ldo + col] = (bf16_t)fast_tanh(acc[i][j][r] + b);
      } else if constexpr (EPI == 1) {
        float* O = (float*)outp;
        const bool dx = (n0 < DIMD);
#pragma unroll
        for (int r = 0; r < 4; ++r) {
          const size_t idx = (size_t)(row + r) * ldo + col;
          if (dx) O[idx] = acc[i][j][r];
          else atomicAdd(&O[idx], -acc[i][j][r]);  // dv_H shares with dvA
        }
      } else {  // EPI 4: h2 fragment-major fp8
        uint8_t* O = (uint8_t*)outp;
        const float b = bias[col];
        const int kb = col >> 6;
        const int khalf = (col >> 5) & 1;
        const int kin = col & 31;
#pragma unroll
        for (int r = 0; r < 4; ++r) {
          const int rw = row + r;
          O[(size_t)((rw >> 5) * 16 + kb) * 2048 +
            (khalf * 32 + (rw & 31)) * 32 + kin] =
              to_fp8(64.f * fast_tanh(acc[i][j][r] + b));
        }
      }
    }
  }
}

// ---------------------------------------------------------------------------
// A3 fused GEMM, MX-fp8, R20: 256 threads / 4 waves, block tile 128x128.
// Wave grid 2x2: each wave 64x64 via 2x2 mfma 32x32x64 (acc[2][2] = 64 AGPR).
// NO LDS, NO BARRIERS: operands stream L2->reg as pre-swizzled fragments.
// Depth-3 pipeline, fully unrolled, named sets s0/s1/s2 loaded directly
// into intx8 halves.  BN=128 = one u-period -> ocol = 128+by.
// ---------------------------------------------------------------------------
__device__ __forceinline__ void a3_body(int bx, int by, const uint8_t* AF,
                                        const uint8_t* BF, float* out,
                                        const float* ab3, const float* uvec) {
  const int tid = threadIdx.x;
  const int wave = tid >> 6;  // 0..3
  const int lane = tid & 63;
  const int wm = wave >> 1;   // 0..1 : 64-row strip
  const int wn = wave & 1;    // 0..1 : 64-col strip
  const int rl = lane & 31;
  const int m0 = bx * 128;
  const int n0 = by * 128;

  // fragment stream base pointers (lane's 32B slice of each 2KB chunk)
  const uint8_t* bp[4];
#pragma unroll
  for (int i = 0; i < 2; ++i)
    bp[i] = AF + (size_t)(bx * 4 + wm * 2 + i) * 16 * 2048 + lane * 32;
#pragma unroll
  for (int j = 0; j < 2; ++j)
    bp[2 + j] = BF + (size_t)(by * 4 + wn * 2 + j) * 16 * 2048 + lane * 32;

  f32x16_t acc[2][2] = {};
  intx8_t s0[4], s1[4], s2[4];

  // load k-block (koff) of all 4 streams straight into intx8 halves
#define A3_LD(S, koff)                                                       \
  _Pragma("unroll") for (int q = 0; q < 4; ++q) {                            \
    *(intx4_t*)&S[q] = *(const intx4_t*)(bp[q] + (koff)*2048);               \
    *((intx4_t*)&S[q] + 1) = *(const intx4_t*)(bp[q] + (koff)*2048 + 16);    \
  }

#define A3_MM(S)                                                             \
  acc[0][0] = __builtin_amdgcn_mfma_scale_f32_32x32x64_f8f6f4(               \
      S[0], S[2], acc[0][0], 0, 0, 0, 0x79797979, 0, 0x79797979);            \
  acc[0][1] = __builtin_amdgcn_mfma_scale_f32_32x32x64_f8f6f4(               \
      S[0], S[3], acc[0][1], 0, 0, 0, 0x79797979, 0, 0x79797979);            \
  acc[1][0] = __builtin_amdgcn_mfma_scale_f32_32x32x64_f8f6f4(               \
      S[1], S[2], acc[1][0], 0, 0, 0, 0x79797979, 0, 0x79797979);            \
  acc[1][1] = __builtin_amdgcn_mfma_scale_f32_32x32x64_f8f6f4(               \
      S[1], S[3], acc[1][1], 0, 0, 0, 0x79797979, 0, 0x79797979);

  A3_LD(s0, 0) A3_LD(s1, 1) A3_LD(s2, 2)
  A3_MM(s0) A3_LD(s0, 3)    // t=0
  A3_MM(s1) A3_LD(s1, 4)    // t=1
  A3_MM(s2) A3_LD(s2, 5)    // t=2
  A3_MM(s0) A3_LD(s0, 6)    // t=3
  A3_MM(s1) A3_LD(s1, 7)    // t=4
  A3_MM(s2) A3_LD(s2, 8)    // t=5
  A3_MM(s0) A3_LD(s0, 9)    // t=6
  A3_MM(s1) A3_LD(s1, 10)   // t=7
  A3_MM(s2) A3_LD(s2, 11)   // t=8
  A3_MM(s0) A3_LD(s0, 12)   // t=9
  A3_MM(s1) A3_LD(s1, 13)   // t=10
  A3_MM(s2) A3_LD(s2, 14)   // t=11
  A3_MM(s0) A3_LD(s0, 15)   // t=12
  A3_MM(s1)                 // t=13
  A3_MM(s2)                 // t=14
  A3_MM(s0)                 // t=15
#undef A3_LD
#undef A3_MM

  // epilogue: C/D col = lane&31, row = (reg&3)+8*(reg>>2)+4*(lane>>5).
  // block's 128 cols are one full u-period -> out column 128+by.
  const int q = lane >> 5;
  float uu[2], b3[2];
#pragma unroll
  for (int j = 0; j < 2; ++j) {
    uu[j] = uvec[wn * 64 + j * 32 + rl];
    b3[j] = ab3[n0 + wn * 64 + j * 32 + rl];
  }
  const int ocol = 128 + by;
#pragma unroll
  for (int i = 0; i < 2; ++i) {
    float s16[16];
#pragma unroll
    for (int r = 0; r < 16; ++r)
      s16[r] = fast_tanh(acc[i][0][r] + b3[0]) * uu[0] +
               fast_tanh(acc[i][1][r] + b3[1]) * uu[1];
#pragma unroll
    for (int r = 0; r < 16; ++r) s16[r] = dpp_sum32(s16[r]);
    if (rl == 31) {  // lanes 31 and 63 hold the two q-half sums
      const int rowb = m0 + wm * 64 + i * 32 + 4 * q;
#pragma unroll
      for (int r = 0; r < 16; ++r)
        atomicAdd(&out[(size_t)(rowb + (r & 3) + 8 * (r >> 2)) * 256 + ocol],
                  s16[r]);
    }
  }
}

// ---------------------------------------------------------------------------
// transposes / cvt helpers
// ---------------------------------------------------------------------------
__device__ __forceinline__ void tcvt_body(char* smem, const float* in,
                                          bf16_t* out, int R, int C, int bx,
                                          int by) {
  float(*t)[33] = (float(*)[33])smem;  // 4224 B
  const int c0 = bx * 32;
  const int r0 = by * 32;
  const int tx = threadIdx.x & 31;
  const int ty = threadIdx.x >> 5;
#pragma unroll
  for (int k = 0; k < 4; ++k)
    t[ty + k * 8][tx] = in[(size_t)(r0 + ty + k * 8) * C + c0 + tx];
  __syncthreads();
#pragma unroll
  for (int k = 0; k < 4; ++k)
    out[(size_t)(c0 + ty + k * 8) * R + r0 + tx] = (bf16_t)t[tx][ty + k * 8];
}

// Aw3 (1024 x 16384) -> fp8 x64, FRAGMENT-MAJOR (Aw3T8F).
// 128x128 tile per block (1024 blocks), float4 reads, cvt_pk packing,
// u32-transposed LDS [128][33]; drain writes fragment chunks:
//   chunk ((cb*16)+kb)*2048, byte (khalf*32 + col%32)*32 + k%32.
__device__ __forceinline__ void aw3t_body(char* smem, const float* Aw3,
                                          uint8_t* Aw3T8F, int b) {
  uint32_t(*T)[33] = (uint32_t(*)[33])smem;  // 16896 B
  const int ct = b & 127;
  const int rt = b >> 7;
  const size_t c0 = (size_t)ct * 128;
  const int r0 = rt * 128;
  const int tx = threadIdx.x & 31;  // col-chunk (4 f32)
  const int g = threadIdx.x >> 5;   // 0..7 row-group
#pragma unroll
  for (int k = 0; k < 4; ++k) {
    const int rr = r0 + 4 * g + 32 * k;
    const float4 v0 = *(const float4*)(Aw3 + (size_t)(rr + 0) * 16384 + c0 + 4 * tx);
    const float4 v1 = *(const float4*)(Aw3 + (size_t)(rr + 1) * 16384 + c0 + 4 * tx);
    const float4 v2 = *(const float4*)(Aw3 + (size_t)(rr + 2) * 16384 + c0 + 4 * tx);
    const float4 v3 = *(const float4*)(Aw3 + (size_t)(rr + 3) * 16384 + c0 + 4 * tx);
    const int r4 = g + 8 * k;  // row/4 within tile (k-dim of output)
    T[4 * tx + 0][r4] = pk4_fp8(64.f * v0.x, 64.f * v1.x, 64.f * v2.x, 64.f * v3.x);
    T[4 * tx + 1][r4] = pk4_fp8(64.f * v0.y, 64.f * v1.y, 64.f * v2.y, 64.f * v3.y);
    T[4 * tx + 2][r4] = pk4_fp8(64.f * v0.z, 64.f * v1.z, 64.f * v2.z, 64.f * v3.z);
    T[4 * tx + 3][r4] = pk4_fp8(64.f * v0.w, 64.f * v1.w, 64.f * v2.w, 64.f * v3.w);
  }
  __syncthreads();
  // T[cc][tx] = 4 fp8 bytes: col = c0+cc, k = r0+4*tx .. +3
  const int kb = (rt << 1) + (tx >> 4);     // k-block (64)
  const int khalf = (tx >> 3) & 1;          // k-half (32)
  const int kin = (tx & 7) << 2;            // k%32 (4-aligned)
#pragma unroll
  for (int k2 = 0; k2 < 16; ++k2) {
    const int cc = g + 8 * k2;
    const int cb = (ct << 2) + (cc >> 5);
    const int cin = cc & 31;
    *(uint32_t*)(Aw3T8F + (size_t)(cb * 16 + kb) * 2048 +
                 (khalf * 32 + cin) * 32 + kin) = T[cc][tx];
  }
}

// one wave handles one row: pre2 = h.Hw2; w_j = s*Hw2_j*(1-h_j^2)
__device__ __forceinline__ void hgrad_row(int row, const bf16_t* h,
                                          const float* Hw2, const float* Hb2,
                                          bf16_t* wout) {
  const int lane = threadIdx.x & 63;
  float hv[10], wv[10];
  float pre2 = 0.f;
#pragma unroll
  for (int t = 0; t < 10; ++t) {
    const int j = lane + t * 64;
    hv[t] = (float)h[(size_t)row * 640 + j];
    wv[t] = Hw2[j];
    pre2 += hv[t] * wv[t];
  }
#pragma unroll
  for (int d = 1; d < 64; d <<= 1) pre2 += __shfl_xor(pre2, d, 64);
  const float y = fast_tanh(pre2 + Hb2[0]);
  const float s = 1.f - y * y;
#pragma unroll
  for (int t = 0; t < 10; ++t) {
    const int j = lane + t * 64;
    wout[(size_t)row * 640 + j] = (bf16_t)(s * wv[t] * (1.f - hv[t] * hv[t]));
  }
}

// ---------------------------------------------------------------------------
// L0: inp cvt (1024) + Hw1T (160) + Aw1T (64) + Aw2T (512) + Hw1_bf cvt (160)
//     + zero-out (1024) = 2944 blocks
// ---------------------------------------------------------------------------
__global__ __launch_bounds__(256) void launch0(
    const float* __restrict__ inp, bf16_t* __restrict__ inp_bf,
    const float* __restrict__ Hw1, bf16_t* __restrict__ Hw1T,
    bf16_t* __restrict__ Hw1_bf, const float* __restrict__ Aw1,
    bf16_t* __restrict__ Aw1T, const float* __restrict__ Aw2,
    bf16_t* __restrict__ Aw2T, float* __restrict__ out) {
  __shared__ __align__(16) char smem[4224];
  int b = blockIdx.x;
  if (b < 1024) {
    const int i = b * 256 + threadIdx.x;
    const float4 v = ((const float4*)inp)[i];
    bf16x4_t o = {(bf16_t)v.x, (bf16_t)v.y, (bf16_t)v.z, (bf16_t)v.w};
    ((bf16x4_t*)inp_bf)[i] = o;
  } else if (b < 1184) {
    int s = b - 1024;
    tcvt_body(smem, Hw1, Hw1T, 256, 640, s % 20, s / 20);
  } else if (b < 1248) {
    int s = b - 1184;
    tcvt_body(smem, Aw1, Aw1T, 128, 512, s % 16, s / 16);
  } else if (b < 1760) {
    int s = b - 1248;
    tcvt_body(smem, Aw2, Aw2T, 512, 1024, s % 32, s / 32);
  } else if (b < 1920) {
    const int i = (b - 1760) * 256 + threadIdx.x;
    const float4 v = ((const float4*)Hw1)[i];
    bf16x4_t o = {(bf16_t)v.x, (bf16_t)v.y, (bf16_t)v.z, (bf16_t)v.w};
    ((bf16x4_t*)Hw1_bf)[i] = o;
  } else {
    const int i = (b - 1920) * 256 + threadIdx.x;
    ((float4*)out)[i] = make_float4(0.f, 0.f, 0.f, 0.f);
  }
}

// ---------------------------------------------------------------------------
// L1: Hfwd 64^2 (640) + A1 64^2 (512) + Aw3T tiles [0,512) = 1664 blocks
// ---------------------------------------------------------------------------
__global__ __launch_bounds__(256) void launch1(
    const bf16_t* __restrict__ inp_bf, const bf16_t* __restrict__ Hw1T,
    const float* __restrict__ Hb1, bf16_t* __restrict__ h_bf,
    const bf16_t* __restrict__ Aw1T, const float* __restrict__ Ab1,
    bf16_t* __restrict__ h1_bf, const float* __restrict__ Aw3,
    uint8_t* __restrict__ Aw3T8F) {
  __shared__ __align__(16) char smem[SMEM_G64];
  const int b = blockIdx.x;
  if (b < 640) {
    gemm64_body<0>(smem, b % 64, b / 64, inp_bf, 256, Hw1T, 256, 256, Hb1,
                   h_bf, 640);
  } else if (b < 1152) {
    const int i = b - 640;
    gemm64_body<0>(smem, i % 64, i / 64, inp_bf, 256, Aw1T, 128, 128, Ab1,
                   h1_bf, 512);
  } else {
    aw3t_body(smem, Aw3, Aw3T8F, b - 1152);  // tiles 0..511
  }
}

// ---------------------------------------------------------------------------
// L2: A2->h2F 64^2 (1024) + hgrad (1024) + Aw3T tiles [512,1024) = 2560
// ---------------------------------------------------------------------------
__global__ __launch_bounds__(256) void launch2(
    const bf16_t* __restrict__ h1_bf, const bf16_t* __restrict__ Aw2T,
    const float* __restrict__ Ab2, uint8_t* __restrict__ h2F,
    const bf16_t* __restrict__ h_bf, const float* __restrict__ Hw2,
    const float* __restrict__ Hb2, bf16_t* __restrict__ w_bf,
    const float* __restrict__ Aw3, uint8_t* __restrict__ Aw3T8F) {
  __shared__ __align__(16) char smem[SMEM_G64];
  const int b = blockIdx.x;
  if (b < 1024) {
    gemm64_body<4>(smem, b % 64, b / 64, h1_bf, 512, Aw2T, 512, 512, Ab2,
                   h2F, 0);
  } else if (b < 2048) {
    const int row = (b - 1024) * 4 + (threadIdx.x >> 6);
    hgrad_row(row, h_bf, Hw2, Hb2, w_bf);
  } else {
    aw3t_body(smem, Aw3, Aw3T8F, 512 + (b - 2048));  // tiles 512..1023
  }
}

// ---------------------------------------------------------------------------
// L3 (256 threads): Hbwd 64^2 4-wave (256) + A3 no-LDS 128x128 (4096) = 4352.
// __launch_bounds__(256,3): 3 blocks/CU = 12 waves (37.5%) -- R19 was
// quantized to 1x8-wave block (23%).
// A3 swizzle: hardware XCD = p%8; each XCD owns 16 contiguous by values
// (B working set 16 x 128KB = 2MB -> L2-resident), bx varies slowest.
// ---------------------------------------------------------------------------
__global__ __launch_bounds__(256, 3) void launch3(
    const bf16_t* __restrict__ w_bf, const bf16_t* __restrict__ Hw1_bf,
    float* __restrict__ out, const uint8_t* __restrict__ h2F,
    const uint8_t* __restrict__ Aw3T8F, const float* __restrict__ Ab3,
    const float* __restrict__ uvec) {
  __shared__ __align__(16) char smem[SMEM3_BYTES];
  const int b = blockIdx.x;
  if (b < 256) {
    gemm64_body<1>(smem, b % 64, b / 64, w_bf, 640, Hw1_bf, 640, 640, nullptr,
                   out, 256);
  } else {
    const int p = b - 256;                          // 0..4095; hw XCD = p % 8
    const int by = (p & 7) * 16 + ((p >> 3) & 15);  // 0..127
    const int bx = p >> 7;                          // 0..31
    a3_body(bx, by, h2F, Aw3T8F, out, Ab3, uvec);
  }
}

// ---------------------------------------------------------------------------
extern "C" void kernel_launch(void* const* d_in, const int* in_sizes, int n_in,
                              void* d_out, int out_size, void* d_ws,
                              size_t ws_size, hipStream_t stream) {
  (void)in_sizes; (void)n_in; (void)out_size; (void)ws_size;
  const float* inp = (const float*)d_in[1];
  const float* Hw1 = (const float*)d_in[2];
  const float* Hb1 = (const float*)d_in[3];
  const float* Hw2 = (const float*)d_in[4];
  const float* Hb2 = (const float*)d_in[5];
  const float* Aw1 = (const float*)d_in[6];
  const float* Ab1 = (const float*)d_in[7];
  const float* Aw2 = (const float*)d_in[8];
  const float* Ab2 = (const float*)d_in[9];
  const float* Aw3 = (const float*)d_in[10];
  const float* Ab3 = (const float*)d_in[11];
  const float* u = (const float*)d_in[12];
  float* out = (float*)d_out;

  char* ws = (char*)d_ws;
  bf16_t* inp_bf = (bf16_t*)ws;    ws += (size_t)NROW * 256 * 2;
  bf16_t* Hw1_bf = (bf16_t*)ws;    ws += (size_t)256 * 640 * 2;
  bf16_t* Hw1T = (bf16_t*)ws;      ws += (size_t)640 * 256 * 2;
  bf16_t* Aw1T = (bf16_t*)ws;      ws += (size_t)512 * 128 * 2;
  bf16_t* Aw2T = (bf16_t*)ws;      ws += (size_t)1024 * 512 * 2;
  uint8_t* Aw3T8F = (uint8_t*)ws;  ws += (size_t)16384 * 1024;
  bf16_t* h_bf = (bf16_t*)ws;      ws += (size_t)NROW * 640 * 2;
  bf16_t* w_bf = (bf16_t*)ws;      ws += (size_t)NROW * 640 * 2;
  bf16_t* h1_bf = (bf16_t*)ws;     ws += (size_t)NROW * 512 * 2;
  uint8_t* h2F = (uint8_t*)ws;     ws += (size_t)NROW * 1024;

  launch0<<<2944, 256, 0, stream>>>(inp, inp_bf, Hw1, Hw1T, Hw1_bf, Aw1, Aw1T,
                                    Aw2, Aw2T, out);
  launch1<<<1664, 256, 0, stream>>>(inp_bf, Hw1T, Hb1, h_bf, Aw1T, Ab1, h1_bf,
                                    Aw3, Aw3T8F);
  launch2<<<2560, 256, 0, stream>>>(h1_bf, Aw2T, Ab2, h2F, h_bf, Hw2, Hb2,
                                    w_bf, Aw3, Aw3T8F);
  launch3<<<4352, 256, 0, stream>>>(w_bf, Hw1_bf, out, h2F, Aw3T8F, Ab3, u);
}

// Round 12
// 232.698 us; speedup vs baseline: 1.1372x; 1.0341x over previous
//
#include <hip/hip_runtime.h>
#include <hip/hip_bf16.h>
#include <cstdint>

// ---------------------------------------------------------------------------
// Hamilton_V5  R21: A3 hybrid operand routing (split the two operand streams
// across the two saturable pipes):
//  - A (h2, 4MB, row-major fp8) -> LDS: g2l16 triple-buffer, shared by both
//    wn-waves (no duplication). Only 4 LDS reads per 4 mfma (R14 had 12).
//  - B (Aw3T8F, 16MB, fragment-major) -> registers: 2 streams x 2 loads,
//    double-buffered bb[t&1], consumed via data dependence.
//  - Pipe budget/CU: MFMA 70K cy, LDS ~80K, VMEM ~62K -- three balanced,
//    overlappable pipes (R14: LDS 115K dominant; R20: VMEM dominant).
//  - Sync: barrier per K-step for the A buffers; manual vmcnt(6)/(4) before
//    the barrier (A(t+2) 2 ops + B(t+1) 4 ops allowed outstanding);
//    in-order vmcnt retirement makes B(t)'s auto-wait also cover A(t+1).
//  - 4-wave 256-thread blocks (launch_bounds(256,3), 3 blocks/CU);
//    geometry/grid/epilogue = R20. h2 producer back to row-major EPI 3.
// ---------------------------------------------------------------------------

typedef __bf16 bf16_t;
typedef __bf16 bf16x4_t __attribute__((ext_vector_type(4)));
typedef __bf16 bf16x8_t __attribute__((ext_vector_type(8)));
typedef float f32x4_t __attribute__((ext_vector_type(4)));
typedef float f32x16_t __attribute__((ext_vector_type(16)));
typedef int intx4_t __attribute__((ext_vector_type(4)));
typedef int intx8_t __attribute__((ext_vector_type(8)));

#define DIMD 128
#define NROW 4096
#define SMEM_G64 24576     // gemm64 3-buf (3*4096*2) ; aw3t 16896 fits
#define SMEM3_BYTES 24576  // hbwd 3-buf ; a3 A-triple 3 x 8192

// branchless tanh: t=2^(2x*log2e); tanh=1-2/(t+1).
__device__ __forceinline__ float fast_tanh(float x) {
  float t = __builtin_amdgcn_exp2f(x * 2.8853900817779268f);
  return 1.f - 2.f * __builtin_amdgcn_rcpf(t + 1.f);
}

// f32 -> fp8 e4m3 (OCP), RNE+sat via HW cvt
__device__ __forceinline__ uint8_t to_fp8(float x) {
  return (uint8_t)(__builtin_amdgcn_cvt_pk_fp8_f32(x, x, 0, false) & 0xff);
}

// pack 4 f32 -> 4 fp8 bytes (byte0=a .. byte3=d) via 2 HW cvt_pk
__device__ __forceinline__ uint32_t pk4_fp8(float a, float b, float c,
                                            float d) {
  uint32_t lo = (uint32_t)__builtin_amdgcn_cvt_pk_fp8_f32(a, b, 0, false);
  return (uint32_t)__builtin_amdgcn_cvt_pk_fp8_f32(c, d, lo, true);
}

// async global->LDS, 16B per lane; LDS dest = wave-uniform base + lane*16
__device__ __forceinline__ void g2l16(const void* gp, void* lp) {
  __builtin_amdgcn_global_load_lds(
      reinterpret_cast<__attribute__((address_space(1))) void*>(
          reinterpret_cast<uintptr_t>(gp)),
      reinterpret_cast<__attribute__((address_space(3))) void*>(
          reinterpret_cast<uintptr_t>(lp)),
      16, 0, 0);
}

// DPP accumulating add (VALU pipe -- no LDS). bound_ctrl=1 => 0-fill.
template <int CTRL>
__device__ __forceinline__ float dpp_addf(float v) {
  return v + __int_as_float(__builtin_amdgcn_update_dpp(
                 0, __float_as_int(v), CTRL, 0xf, 0xf, true));
}
// sum over each 32-lane half; result in lane 31 (half 0) / lane 63 (half 1).
__device__ __forceinline__ float dpp_sum32(float v) {
  v = dpp_addf<0x111>(v);  // row_shr:1
  v = dpp_addf<0x112>(v);  // row_shr:2
  v = dpp_addf<0x114>(v);  // row_shr:4
  v = dpp_addf<0x118>(v);  // row_shr:8  -> lane15/31/47/63 = row sums
  v = dpp_addf<0x142>(v);  // row_bcast15 -> lane31/63 = 32-lane sums
  return v;
}

// ---------------------------------------------------------------------------
// bf16 GEMM, 64x64 tile, BK=32, 4 waves 2x2 (each 32x32 = 2x2 mfma 16x16x32).
// Triple-buffered LDS, depth-2 prefetch, counted vmcnt(2) per step.
// EPI 0: bf16 tanh(C+b); EPI 1: dx store / dv atomicAdd(-C);
// EPI 3: fp8 x64 row-major.  (256-thread launches.)
// ---------------------------------------------------------------------------
template <int EPI>
__device__ __forceinline__ void gemm64_body(char* smem, int bx, int by,
                                            const bf16_t* A, int lda,
                                            const bf16_t* B, int ldb, int K,
                                            const float* bias, void* outp,
                                            int ldo) {
  constexpr int BK = 32;
  bf16_t* As = (bf16_t*)smem;   // 3 x 64*32
  bf16_t* Bs = As + 3 * 2048;   // 3 x 64*32
  const int NT = K / BK;

  const int m0 = bx * 64;
  const int n0 = by * 64;
  const int tid = threadIdx.x;
  const int wave = tid >> 6;
  const int lane = tid & 63;
  const int wm = wave >> 1;
  const int wn = wave & 1;

  const int sr = lane >> 2;
  const int sk = (((lane & 3) ^ ((sr >> 1) & 3)) * 8);
  const int fr = lane & 15;
  const int fk = (((lane >> 4) ^ ((fr >> 1) & 3)) * 8);
  const int rb = wave * 16;  // each wave stages 16 rows of A and B

  const bf16_t* Ag = A + (size_t)(m0 + rb + sr) * lda + sk;
  const bf16_t* Bg = B + (size_t)(n0 + rb + sr) * ldb + sk;

#define G64_STAGE(buf, k0)                              \
  do {                                                  \
    g2l16(Ag + (k0), As + (buf) * 2048 + rb * BK);      \
    g2l16(Bg + (k0), Bs + (buf) * 2048 + rb * BK);      \
  } while (0)

  f32x4_t acc[2][2] = {};

  G64_STAGE(0, 0);
  G64_STAGE(1, BK);
  asm volatile("s_waitcnt vmcnt(2)" ::: "memory");
  __builtin_amdgcn_s_barrier();
  asm volatile("" ::: "memory");

  for (int t = 0; t < NT; ++t) {
    if (t + 2 < NT) G64_STAGE((t + 2) % 3, (t + 2) * BK);
    const bf16_t* Ab = As + (t % 3) * 2048;
    const bf16_t* Bb = Bs + (t % 3) * 2048;

    bf16x8_t af[2], bb[2];
#pragma unroll
    for (int u = 0; u < 2; ++u) {
      af[u] = *(const bf16x8_t*)(Ab + (wm * 32 + u * 16 + fr) * BK + fk);
      bb[u] = *(const bf16x8_t*)(Bb + (wn * 32 + u * 16 + fr) * BK + fk);
    }
#pragma unroll
    for (int i = 0; i < 2; ++i)
#pragma unroll
      for (int j = 0; j < 2; ++j)
        acc[i][j] = __builtin_amdgcn_mfma_f32_16x16x32_bf16(af[i], bb[j],
                                                            acc[i][j], 0, 0, 0);
    if (t < NT - 1) {
      if (t + 2 < NT)
        asm volatile("s_waitcnt vmcnt(2)" ::: "memory");
      else
        asm volatile("s_waitcnt vmcnt(0)" ::: "memory");
      __builtin_amdgcn_s_barrier();
      asm volatile("" ::: "memory");
    }
  }
#undef G64_STAGE

  // C/D layout (m89): col = lane&15, row = (lane>>4)*4 + reg
#pragma unroll
  for (int i = 0; i < 2; ++i) {
    const int row = m0 + wm * 32 + i * 16 + (lane >> 4) * 4;
#pragma unroll
    for (int j = 0; j < 2; ++j) {
      const int col = n0 + wn * 32 + j * 16 + fr;
      if constexpr (EPI == 0) {
        bf16_t* O = (bf16_t*)outp;
        const float b = bias[col];
#pragma unroll
        for (int r = 0; r < 4; ++r)
          O[(size_t)(row + r) * ldo + col] = (bf16_t)fast_tanh(acc[i][j][r] + b);
      } else if constexpr (EPI == 1) {
        float* O = (float*)outp;
        const bool dx = (n0 < DIMD);
#pragma unroll
        for (int r = 0; r < 4; ++r) {
          const size_t idx = (size_t)(row + r) * ldo + col;
          if (dx) O[idx] = acc[i][j][r];
          else atomicAdd(&O[idx], -acc[i][j][r]);  // dv_H shares with dvA
        }
      } else {  // EPI 3: fp8 x64 row-major
        uint8_t* O = (uint8_t*)outp;
        const float b = bias[col];
#pragma unroll
        for (int r = 0; r < 4; ++r)
          O[(size_t)(row + r) * ldo + col] =
              to_fp8(64.f * fast_tanh(acc[i][j][r] + b));
      }
    }
  }
}

// ---------------------------------------------------------------------------
// A3 fused GEMM, MX-fp8, R21 hybrid: 256 threads / 4 waves, tile 128x128.
// Wave grid 2x2: each wave 64x64 via 2x2 mfma 32x32x64 (acc[2][2] = 64 AGPR).
// A (row-major h2_f8): LDS triple-buffer via g2l16, R14 chunk-swizzle,
//   shared across wn-waves (no dup).  4 LDS reads / 4 mfma per step.
// B (fragment Aw3T8F): register double-buffer bb[t&1], 4 loads/step.
// Barrier per K-step; vmcnt(6)/(4) counted (A(t+2)=2 + B(t+1)=4 in flight).
// ---------------------------------------------------------------------------
__device__ __forceinline__ void a3_body(char* smem, int bx, int by,
                                        const uint8_t* Arow,
                                        const uint8_t* BF, float* out,
                                        const float* ab3, const float* uvec) {
  constexpr int NT = 16;
  uint8_t* As = (uint8_t*)smem;  // 3 x 128*64 = 24576

  const int tid = threadIdx.x;
  const int wave = tid >> 6;  // 0..3
  const int lane = tid & 63;
  const int wm = wave >> 1;   // 0..1 : 64-row strip
  const int wn = wave & 1;    // 0..1 : 64-col strip
  const int rl = lane & 31;
  const int c0 = lane >> 5;
  const int m0 = bx * 128;
  const int n0 = by * 128;

  // ---- A staging (row-major, 16B chunk-swizzle: chunk c of row r at slot
  // c ^ ((r>>1)&3); LDS linear dest = wave-uniform base + lane*16) ----
  const int sr = lane >> 2;  // 0..15 row within 16-row stage chunk
  const int sk = ((lane & 3) ^ ((sr >> 1) & 3)) * 16;
  const uint8_t* Ag = Arow + (size_t)(m0 + wave * 32 + sr) * 1024 + sk;
  const int lbase = wave * 2048;  // wave's 32 rows = 2KB per buffer

#define A3_STAGE(buf, k0)                                                \
  do {                                                                   \
    g2l16(Ag + (size_t)(k0) * 64, As + (buf) * 8192 + lbase);            \
    g2l16(Ag + 16 * 1024 + (size_t)(k0) * 64,                            \
          As + (buf) * 8192 + lbase + 1024);                             \
  } while (0)

  // ---- B fragment streams (2 per wave), register double-buffer ----
  const uint8_t* Bg0 = BF + (size_t)(by * 4 + wn * 2 + 0) * 16 * 2048 + lane * 32;
  const uint8_t* Bg1 = BF + (size_t)(by * 4 + wn * 2 + 1) * 16 * 2048 + lane * 32;

  f32x16_t acc[2][2] = {};
  intx8_t bb[2][2];  // [t&1][j]

#define B_LOAD(par, t)                                                    \
  do {                                                                    \
    *(intx4_t*)&bb[par][0] = *(const intx4_t*)(Bg0 + (size_t)(t) * 2048); \
    *((intx4_t*)&bb[par][0] + 1) =                                        \
        *(const intx4_t*)(Bg0 + (size_t)(t) * 2048 + 16);                 \
    *(intx4_t*)&bb[par][1] = *(const intx4_t*)(Bg1 + (size_t)(t) * 2048); \
    *((intx4_t*)&bb[par][1] + 1) =                                        \
        *(const intx4_t*)(Bg1 + (size_t)(t) * 2048 + 16);                 \
  } while (0)

  // prologue: stage A(0),A(1); load B(0). A(0) done when <=6 outstanding.
  A3_STAGE(0, 0);
  A3_STAGE(1, 1);
  B_LOAD(0, 0);
  asm volatile("s_waitcnt vmcnt(6)" ::: "memory");
  __builtin_amdgcn_s_barrier();
  asm volatile("" ::: "memory");

  const int w = (rl >> 1) & 3;
  const int sLo = ((2 * c0) ^ w) * 16;
  const int sHi = ((2 * c0 + 1) ^ w) * 16;

#pragma unroll
  for (int t = 0; t < NT; ++t) {
    if (t + 2 < NT) A3_STAGE((t + 2) % 3, t + 2);
    if (t + 1 < NT) B_LOAD((t + 1) & 1, t + 1);
    const uint8_t* Ab = As + (t % 3) * 8192;
#pragma unroll
    for (int i = 0; i < 2; ++i) {
      const int ra = (wm * 64 + i * 32 + rl) * 64;
      intx8_t af;
      *(intx4_t*)&af = *(const intx4_t*)(Ab + ra + sLo);
      *((intx4_t*)&af + 1) = *(const intx4_t*)(Ab + ra + sHi);
#pragma unroll
      for (int j = 0; j < 2; ++j)
        acc[i][j] = __builtin_amdgcn_mfma_scale_f32_32x32x64_f8f6f4(
            af, bb[t & 1][j], acc[i][j], 0, 0, 0, 0x79797979, 0, 0x79797979);
    }
    if (t < NT - 1) {
      if (t + 2 < NT)
        asm volatile("s_waitcnt vmcnt(6)" ::: "memory");
      else
        asm volatile("s_waitcnt vmcnt(4)" ::: "memory");
      __builtin_amdgcn_s_barrier();
      asm volatile("" ::: "memory");
    }
  }
#undef A3_STAGE
#undef B_LOAD

  // epilogue: C/D col = lane&31, row = (reg&3)+8*(reg>>2)+4*(lane>>5).
  // block's 128 cols are one full u-period -> out column 128+by.
  const int q = lane >> 5;
  float uu[2], b3[2];
#pragma unroll
  for (int j = 0; j < 2; ++j) {
    uu[j] = uvec[wn * 64 + j * 32 + rl];
    b3[j] = ab3[n0 + wn * 64 + j * 32 + rl];
  }
  const int ocol = 128 + by;
#pragma unroll
  for (int i = 0; i < 2; ++i) {
    float s16[16];
#pragma unroll
    for (int r = 0; r < 16; ++r)
      s16[r] = fast_tanh(acc[i][0][r] + b3[0]) * uu[0] +
               fast_tanh(acc[i][1][r] + b3[1]) * uu[1];
#pragma unroll
    for (int r = 0; r < 16; ++r) s16[r] = dpp_sum32(s16[r]);
    if (rl == 31) {  // lanes 31 and 63 hold the two q-half sums
      const int rowb = m0 + wm * 64 + i * 32 + 4 * q;
#pragma unroll
      for (int r = 0; r < 16; ++r)
        atomicAdd(&out[(size_t)(rowb + (r & 3) + 8 * (r >> 2)) * 256 + ocol],
                  s16[r]);
    }
  }
}

// ---------------------------------------------------------------------------
// transposes / cvt helpers
// ---------------------------------------------------------------------------
__device__ __forceinline__ void tcvt_body(char* smem, const float* in,
                                          bf16_t* out, int R, int C, int bx,
                                          int by) {
  float(*t)[33] = (float(*)[33])smem;  // 4224 B
  const int c0 = bx * 32;
  const int r0 = by * 32;
  const int tx = threadIdx.x & 31;
  const int ty = threadIdx.x >> 5;
#pragma unroll
  for (int k = 0; k < 4; ++k)
    t[ty + k * 8][tx] = in[(size_t)(r0 + ty + k * 8) * C + c0 + tx];
  __syncthreads();
#pragma unroll
  for (int k = 0; k < 4; ++k)
    out[(size_t)(c0 + ty + k * 8) * R + r0 + tx] = (bf16_t)t[tx][ty + k * 8];
}

// Aw3 (1024 x 16384) -> fp8 x64, FRAGMENT-MAJOR (Aw3T8F).
// 128x128 tile per block (1024 blocks), float4 reads, cvt_pk packing,
// u32-transposed LDS [128][33]; drain writes fragment chunks:
//   chunk ((cb*16)+kb)*2048, byte (khalf*32 + col%32)*32 + k%32.
__device__ __forceinline__ void aw3t_body(char* smem, const float* Aw3,
                                          uint8_t* Aw3T8F, int b) {
  uint32_t(*T)[33] = (uint32_t(*)[33])smem;  // 16896 B
  const int ct = b & 127;
  const int rt = b >> 7;
  const size_t c0 = (size_t)ct * 128;
  const int r0 = rt * 128;
  const int tx = threadIdx.x & 31;  // col-chunk (4 f32)
  const int g = threadIdx.x >> 5;   // 0..7 row-group
#pragma unroll
  for (int k = 0; k < 4; ++k) {
    const int rr = r0 + 4 * g + 32 * k;
    const float4 v0 = *(const float4*)(Aw3 + (size_t)(rr + 0) * 16384 + c0 + 4 * tx);
    const float4 v1 = *(const float4*)(Aw3 + (size_t)(rr + 1) * 16384 + c0 + 4 * tx);
    const float4 v2 = *(const float4*)(Aw3 + (size_t)(rr + 2) * 16384 + c0 + 4 * tx);
    const float4 v3 = *(const float4*)(Aw3 + (size_t)(rr + 3) * 16384 + c0 + 4 * tx);
    const int r4 = g + 8 * k;  // row/4 within tile (k-dim of output)
    T[4 * tx + 0][r4] = pk4_fp8(64.f * v0.x, 64.f * v1.x, 64.f * v2.x, 64.f * v3.x);
    T[4 * tx + 1][r4] = pk4_fp8(64.f * v0.y, 64.f * v1.y, 64.f * v2.y, 64.f * v3.y);
    T[4 * tx + 2][r4] = pk4_fp8(64.f * v0.z, 64.f * v1.z, 64.f * v2.z, 64.f * v3.z);
    T[4 * tx + 3][r4] = pk4_fp8(64.f * v0.w, 64.f * v1.w, 64.f * v2.w, 64.f * v3.w);
  }
  __syncthreads();
  // T[cc][tx] = 4 fp8 bytes: col = c0+cc, k = r0+4*tx .. +3
  const int kb = (rt << 1) + (tx >> 4);     // k-block (64)
  const int khalf = (tx >> 3) & 1;          // k-half (32)
  const int kin = (tx & 7) << 2;            // k%32 (4-aligned)
#pragma unroll
  for (int k2 = 0; k2 < 16; ++k2) {
    const int cc = g + 8 * k2;
    const int cb = (ct << 2) + (cc >> 5);
    const int cin = cc & 31;
    *(uint32_t*)(Aw3T8F + (size_t)(cb * 16 + kb) * 2048 +
                 (khalf * 32 + cin) * 32 + kin) = T[cc][tx];
  }
}

// one wave handles one row: pre2 = h.Hw2; w_j = s*Hw2_j*(1-h_j^2)
__device__ __forceinline__ void hgrad_row(int row, const bf16_t* h,
                                          const float* Hw2, const float* Hb2,
                                          bf16_t* wout) {
  const int lane = threadIdx.x & 63;
  float hv[10], wv[10];
  float pre2 = 0.f;
#pragma unroll
  for (int t = 0; t < 10; ++t) {
    const int j = lane + t * 64;
    hv[t] = (float)h[(size_t)row * 640 + j];
    wv[t] = Hw2[j];
    pre2 += hv[t] * wv[t];
  }
#pragma unroll
  for (int d = 1; d < 64; d <<= 1) pre2 += __shfl_xor(pre2, d, 64);
  const float y = fast_tanh(pre2 + Hb2[0]);
  const float s = 1.f - y * y;
#pragma unroll
  for (int t = 0; t < 10; ++t) {
    const int j = lane + t * 64;
    wout[(size_t)row * 640 + j] = (bf16_t)(s * wv[t] * (1.f - hv[t] * hv[t]));
  }
}

// ---------------------------------------------------------------------------
// L0: inp cvt (1024) + Hw1T (160) + Aw1T (64) + Aw2T (512) + Hw1_bf cvt (160)
//     + zero-out (1024) = 2944 blocks
// ---------------------------------------------------------------------------
__global__ __launch_bounds__(256) void launch0(
    const float* __restrict__ inp, bf16_t* __restrict__ inp_bf,
    const float* __restrict__ Hw1, bf16_t* __restrict__ Hw1T,
    bf16_t* __restrict__ Hw1_bf, const float* __restrict__ Aw1,
    bf16_t* __restrict__ Aw1T, const float* __restrict__ Aw2,
    bf16_t* __restrict__ Aw2T, float* __restrict__ out) {
  __shared__ __align__(16) char smem[4224];
  int b = blockIdx.x;
  if (b < 1024) {
    const int i = b * 256 + threadIdx.x;
    const float4 v = ((const float4*)inp)[i];
    bf16x4_t o = {(bf16_t)v.x, (bf16_t)v.y, (bf16_t)v.z, (bf16_t)v.w};
    ((bf16x4_t*)inp_bf)[i] = o;
  } else if (b < 1184) {
    int s = b - 1024;
    tcvt_body(smem, Hw1, Hw1T, 256, 640, s % 20, s / 20);
  } else if (b < 1248) {
    int s = b - 1184;
    tcvt_body(smem, Aw1, Aw1T, 128, 512, s % 16, s / 16);
  } else if (b < 1760) {
    int s = b - 1248;
    tcvt_body(smem, Aw2, Aw2T, 512, 1024, s % 32, s / 32);
  } else if (b < 1920) {
    const int i = (b - 1760) * 256 + threadIdx.x;
    const float4 v = ((const float4*)Hw1)[i];
    bf16x4_t o = {(bf16_t)v.x, (bf16_t)v.y, (bf16_t)v.z, (bf16_t)v.w};
    ((bf16x4_t*)Hw1_bf)[i] = o;
  } else {
    const int i = (b - 1920) * 256 + threadIdx.x;
    ((float4*)out)[i] = make_float4(0.f, 0.f, 0.f, 0.f);
  }
}

// ---------------------------------------------------------------------------
// L1: Hfwd 64^2 (640) + A1 64^2 (512) + Aw3T tiles [0,512) = 1664 blocks
// ---------------------------------------------------------------------------
__global__ __launch_bounds__(256) void launch1(
    const bf16_t* __restrict__ inp_bf, const bf16_t* __restrict__ Hw1T,
    const float* __restrict__ Hb1, bf16_t* __restrict__ h_bf,
    const bf16_t* __restrict__ Aw1T, const float* __restrict__ Ab1,
    bf16_t* __restrict__ h1_bf, const float* __restrict__ Aw3,
    uint8_t* __restrict__ Aw3T8F) {
  __shared__ __align__(16) char smem[SMEM_G64];
  const int b = blockIdx.x;
  if (b < 640) {
    gemm64_body<0>(smem, b % 64, b / 64, inp_bf, 256, Hw1T, 256, 256, Hb1,
                   h_bf, 640);
  } else if (b < 1152) {
    const int i = b - 640;
    gemm64_body<0>(smem, i % 64, i / 64, inp_bf, 256, Aw1T, 128, 128, Ab1,
                   h1_bf, 512);
  } else {
    aw3t_body(smem, Aw3, Aw3T8F, b - 1152);  // tiles 0..511
  }
}

// ---------------------------------------------------------------------------
// L2: A2->fp8 row-major (1024) + hgrad (1024) + Aw3T tiles [512,1024) = 2560
// ---------------------------------------------------------------------------
__global__ __launch_bounds__(256) void launch2(
    const bf16_t* __restrict__ h1_bf, const bf16_t* __restrict__ Aw2T,
    const float* __restrict__ Ab2, uint8_t* __restrict__ h2_f8,
    const bf16_t* __restrict__ h_bf, const float* __restrict__ Hw2,
    const float* __restrict__ Hb2, bf16_t* __restrict__ w_bf,
    const float* __restrict__ Aw3, uint8_t* __restrict__ Aw3T8F) {
  __shared__ __align__(16) char smem[SMEM_G64];
  const int b = blockIdx.x;
  if (b < 1024) {
    gemm64_body<3>(smem, b % 64, b / 64, h1_bf, 512, Aw2T, 512, 512, Ab2,
                   h2_f8, 1024);
  } else if (b < 2048) {
    const int row = (b - 1024) * 4 + (threadIdx.x >> 6);
    hgrad_row(row, h_bf, Hw2, Hb2, w_bf);
  } else {
    aw3t_body(smem, Aw3, Aw3T8F, 512 + (b - 2048));  // tiles 512..1023
  }
}

// ---------------------------------------------------------------------------
// L3 (256 threads): Hbwd 64^2 4-wave (256) + A3 hybrid 128x128 (4096) = 4352.
// __launch_bounds__(256,3): 3 blocks/CU = 12 waves.
// A3 swizzle: hardware XCD = p%8; each XCD owns 16 contiguous by values
// (B working set 16 x 128KB = 2MB -> L2-resident), bx varies slowest.
// ---------------------------------------------------------------------------
__global__ __launch_bounds__(256, 3) void launch3(
    const bf16_t* __restrict__ w_bf, const bf16_t* __restrict__ Hw1_bf,
    float* __restrict__ out, const uint8_t* __restrict__ h2_f8,
    const uint8_t* __restrict__ Aw3T8F, const float* __restrict__ Ab3,
    const float* __restrict__ uvec) {
  __shared__ __align__(16) char smem[SMEM3_BYTES];
  const int b = blockIdx.x;
  if (b < 256) {
    gemm64_body<1>(smem, b % 64, b / 64, w_bf, 640, Hw1_bf, 640, 640, nullptr,
                   out, 256);
  } else {
    const int p = b - 256;                          // 0..4095; hw XCD = p % 8
    const int by = (p & 7) * 16 + ((p >> 3) & 15);  // 0..127
    const int bx = p >> 7;                          // 0..31
    a3_body(smem, bx, by, h2_f8, Aw3T8F, out, Ab3, uvec);
  }
}

// ---------------------------------------------------------------------------
extern "C" void kernel_launch(void* const* d_in, const int* in_sizes, int n_in,
                              void* d_out, int out_size, void* d_ws,
                              size_t ws_size, hipStream_t stream) {
  (void)in_sizes; (void)n_in; (void)out_size; (void)ws_size;
  const float* inp = (const float*)d_in[1];
  const float* Hw1 = (const float*)d_in[2];
  const float* Hb1 = (const float*)d_in[3];
  const float* Hw2 = (const float*)d_in[4];
  const float* Hb2 = (const float*)d_in[5];
  const float* Aw1 = (const float*)d_in[6];
  const float* Ab1 = (const float*)d_in[7];
  const float* Aw2 = (const float*)d_in[8];
  const float* Ab2 = (const float*)d_in[9];
  const float* Aw3 = (const float*)d_in[10];
  const float* Ab3 = (const float*)d_in[11];
  const float* u = (const float*)d_in[12];
  float* out = (float*)d_out;

  char* ws = (char*)d_ws;
  bf16_t* inp_bf = (bf16_t*)ws;    ws += (size_t)NROW * 256 * 2;
  bf16_t* Hw1_bf = (bf16_t*)ws;    ws += (size_t)256 * 640 * 2;
  bf16_t* Hw1T = (bf16_t*)ws;      ws += (size_t)640 * 256 * 2;
  bf16_t* Aw1T = (bf16_t*)ws;      ws += (size_t)512 * 128 * 2;
  bf16_t* Aw2T = (bf16_t*)ws;      ws += (size_t)1024 * 512 * 2;
  uint8_t* Aw3T8F = (uint8_t*)ws;  ws += (size_t)16384 * 1024;
  bf16_t* h_bf = (bf16_t*)ws;      ws += (size_t)NROW * 640 * 2;
  bf16_t* w_bf = (bf16_t*)ws;      ws += (size_t)NROW * 640 * 2;
  bf16_t* h1_bf = (bf16_t*)ws;     ws += (size_t)NROW * 512 * 2;
  uint8_t* h2_f8 = (uint8_t*)ws;   ws += (size_t)NROW * 1024;

  launch0<<<2944, 256, 0, stream>>>(inp, inp_bf, Hw1, Hw1T, Hw1_bf, Aw1, Aw1T,
                                    Aw2, Aw2T, out);
  launch1<<<1664, 256, 0, stream>>>(inp_bf, Hw1T, Hb1, h_bf, Aw1T, Ab1, h1_bf,
                                    Aw3, Aw3T8F);
  launch2<<<2560, 256, 0, stream>>>(h1_bf, Aw2T, Ab2, h2_f8, h_bf, Hw2, Hb2,
                                    w_bf, Aw3, Aw3T8F);
  launch3<<<4352, 256, 0, stream>>>(w_bf, Hw1_bf, out, h2_f8, Aw3T8F, Ab3, u);
}

// Round 13
// 227.901 us; speedup vs baseline: 1.1611x; 1.0210x over previous
//
#include <hip/hip_runtime.h>
#include <hip/hip_bf16.h>
#include <cstdint>

// ---------------------------------------------------------------------------
// Hamilton_V5  R22 = R21 hybrid with BK 64 -> 128 (halve A3 barrier count):
//  - R21 accounting: MFMA 70K + VALU 82K of 234K cy/CU -> ~34% barrier-drain
//    across 16 K-step barriers. BK=128 -> 8 steps / 8 barriers.
//  - Per step: A stages 2 k-halves (4 g2l16, 16KB tile, LDS 3x16KB=48KB,
//    still 3 blocks/CU), B loads 2 chunks/stream (8 loads, bb[2][2][2]
//    double-buffer = 64 VGPR), 8 mfma. vmcnt(12) steady / vmcnt(8) tail.
//  - Everything else byte-identical to R21 (producers, hbwd, L0/L1/L2,
//    grids, swizzles, epilogue).
// ---------------------------------------------------------------------------

typedef __bf16 bf16_t;
typedef __bf16 bf16x4_t __attribute__((ext_vector_type(4)));
typedef __bf16 bf16x8_t __attribute__((ext_vector_type(8)));
typedef float f32x4_t __attribute__((ext_vector_type(4)));
typedef float f32x16_t __attribute__((ext_vector_type(16)));
typedef int intx4_t __attribute__((ext_vector_type(4)));
typedef int intx8_t __attribute__((ext_vector_type(8)));

#define DIMD 128
#define NROW 4096
#define SMEM_G64 24576     // gemm64 3-buf (3*4096*2) ; aw3t 16896 fits
#define SMEM3_BYTES 49152  // a3: 3 x 16384 (A tiles); hbwd uses 24576

// branchless tanh: t=2^(2x*log2e); tanh=1-2/(t+1).
__device__ __forceinline__ float fast_tanh(float x) {
  float t = __builtin_amdgcn_exp2f(x * 2.8853900817779268f);
  return 1.f - 2.f * __builtin_amdgcn_rcpf(t + 1.f);
}

// f32 -> fp8 e4m3 (OCP), RNE+sat via HW cvt
__device__ __forceinline__ uint8_t to_fp8(float x) {
  return (uint8_t)(__builtin_amdgcn_cvt_pk_fp8_f32(x, x, 0, false) & 0xff);
}

// pack 4 f32 -> 4 fp8 bytes (byte0=a .. byte3=d) via 2 HW cvt_pk
__device__ __forceinline__ uint32_t pk4_fp8(float a, float b, float c,
                                            float d) {
  uint32_t lo = (uint32_t)__builtin_amdgcn_cvt_pk_fp8_f32(a, b, 0, false);
  return (uint32_t)__builtin_amdgcn_cvt_pk_fp8_f32(c, d, lo, true);
}

// async global->LDS, 16B per lane; LDS dest = wave-uniform base + lane*16
__device__ __forceinline__ void g2l16(const void* gp, void* lp) {
  __builtin_amdgcn_global_load_lds(
      reinterpret_cast<__attribute__((address_space(1))) void*>(
          reinterpret_cast<uintptr_t>(gp)),
      reinterpret_cast<__attribute__((address_space(3))) void*>(
          reinterpret_cast<uintptr_t>(lp)),
      16, 0, 0);
}

// DPP accumulating add (VALU pipe -- no LDS). bound_ctrl=1 => 0-fill.
template <int CTRL>
__device__ __forceinline__ float dpp_addf(float v) {
  return v + __int_as_float(__builtin_amdgcn_update_dpp(
                 0, __float_as_int(v), CTRL, 0xf, 0xf, true));
}
// sum over each 32-lane half; result in lane 31 (half 0) / lane 63 (half 1).
__device__ __forceinline__ float dpp_sum32(float v) {
  v = dpp_addf<0x111>(v);  // row_shr:1
  v = dpp_addf<0x112>(v);  // row_shr:2
  v = dpp_addf<0x114>(v);  // row_shr:4
  v = dpp_addf<0x118>(v);  // row_shr:8  -> lane15/31/47/63 = row sums
  v = dpp_addf<0x142>(v);  // row_bcast15 -> lane31/63 = 32-lane sums
  return v;
}

// ---------------------------------------------------------------------------
// bf16 GEMM, 64x64 tile, BK=32, 4 waves 2x2 (each 32x32 = 2x2 mfma 16x16x32).
// Triple-buffered LDS, depth-2 prefetch, counted vmcnt(2) per step.
// EPI 0: bf16 tanh(C+b); EPI 1: dx store / dv atomicAdd(-C);
// EPI 3: fp8 x64 row-major.  (256-thread launches.)
// ---------------------------------------------------------------------------
template <int EPI>
__device__ __forceinline__ void gemm64_body(char* smem, int bx, int by,
                                            const bf16_t* A, int lda,
                                            const bf16_t* B, int ldb, int K,
                                            const float* bias, void* outp,
                                            int ldo) {
  constexpr int BK = 32;
  bf16_t* As = (bf16_t*)smem;   // 3 x 64*32
  bf16_t* Bs = As + 3 * 2048;   // 3 x 64*32
  const int NT = K / BK;

  const int m0 = bx * 64;
  const int n0 = by * 64;
  const int tid = threadIdx.x;
  const int wave = tid >> 6;
  const int lane = tid & 63;
  const int wm = wave >> 1;
  const int wn = wave & 1;

  const int sr = lane >> 2;
  const int sk = (((lane & 3) ^ ((sr >> 1) & 3)) * 8);
  const int fr = lane & 15;
  const int fk = (((lane >> 4) ^ ((fr >> 1) & 3)) * 8);
  const int rb = wave * 16;  // each wave stages 16 rows of A and B

  const bf16_t* Ag = A + (size_t)(m0 + rb + sr) * lda + sk;
  const bf16_t* Bg = B + (size_t)(n0 + rb + sr) * ldb + sk;

#define G64_STAGE(buf, k0)                              \
  do {                                                  \
    g2l16(Ag + (k0), As + (buf) * 2048 + rb * BK);      \
    g2l16(Bg + (k0), Bs + (buf) * 2048 + rb * BK);      \
  } while (0)

  f32x4_t acc[2][2] = {};

  G64_STAGE(0, 0);
  G64_STAGE(1, BK);
  asm volatile("s_waitcnt vmcnt(2)" ::: "memory");
  __builtin_amdgcn_s_barrier();
  asm volatile("" ::: "memory");

  for (int t = 0; t < NT; ++t) {
    if (t + 2 < NT) G64_STAGE((t + 2) % 3, (t + 2) * BK);
    const bf16_t* Ab = As + (t % 3) * 2048;
    const bf16_t* Bb = Bs + (t % 3) * 2048;

    bf16x8_t af[2], bb[2];
#pragma unroll
    for (int u = 0; u < 2; ++u) {
      af[u] = *(const bf16x8_t*)(Ab + (wm * 32 + u * 16 + fr) * BK + fk);
      bb[u] = *(const bf16x8_t*)(Bb + (wn * 32 + u * 16 + fr) * BK + fk);
    }
#pragma unroll
    for (int i = 0; i < 2; ++i)
#pragma unroll
      for (int j = 0; j < 2; ++j)
        acc[i][j] = __builtin_amdgcn_mfma_f32_16x16x32_bf16(af[i], bb[j],
                                                            acc[i][j], 0, 0, 0);
    if (t < NT - 1) {
      if (t + 2 < NT)
        asm volatile("s_waitcnt vmcnt(2)" ::: "memory");
      else
        asm volatile("s_waitcnt vmcnt(0)" ::: "memory");
      __builtin_amdgcn_s_barrier();
      asm volatile("" ::: "memory");
    }
  }
#undef G64_STAGE

  // C/D layout (m89): col = lane&15, row = (lane>>4)*4 + reg
#pragma unroll
  for (int i = 0; i < 2; ++i) {
    const int row = m0 + wm * 32 + i * 16 + (lane >> 4) * 4;
#pragma unroll
    for (int j = 0; j < 2; ++j) {
      const int col = n0 + wn * 32 + j * 16 + fr;
      if constexpr (EPI == 0) {
        bf16_t* O = (bf16_t*)outp;
        const float b = bias[col];
#pragma unroll
        for (int r = 0; r < 4; ++r)
          O[(size_t)(row + r) * ldo + col] = (bf16_t)fast_tanh(acc[i][j][r] + b);
      } else if constexpr (EPI == 1) {
        float* O = (float*)outp;
        const bool dx = (n0 < DIMD);
#pragma unroll
        for (int r = 0; r < 4; ++r) {
          const size_t idx = (size_t)(row + r) * ldo + col;
          if (dx) O[idx] = acc[i][j][r];
          else atomicAdd(&O[idx], -acc[i][j][r]);  // dv_H shares with dvA
        }
      } else {  // EPI 3: fp8 x64 row-major
        uint8_t* O = (uint8_t*)outp;
        const float b = bias[col];
#pragma unroll
        for (int r = 0; r < 4; ++r)
          O[(size_t)(row + r) * ldo + col] =
              to_fp8(64.f * fast_tanh(acc[i][j][r] + b));
      }
    }
  }
}

// ---------------------------------------------------------------------------
// A3 fused GEMM, MX-fp8, R22 hybrid BK=128: 256 threads / 4 waves, 128x128.
// Wave grid 2x2: each wave 64x64 via 2x2 mfma 32x32x64 (acc[2][2] = 64 AGPR).
// A (row-major h2_f8): LDS triple-buffer (16KB tiles, 2 k-halves), shared.
// B (fragment Aw3T8F): register double-buffer bb[par][khalf][j].
// 8 K-steps, 8 barriers; vmcnt(12) steady / vmcnt(8) tail.
// ---------------------------------------------------------------------------
__device__ __forceinline__ void a3_body(char* smem, int bx, int by,
                                        const uint8_t* Arow,
                                        const uint8_t* BF, float* out,
                                        const float* ab3, const float* uvec) {
  constexpr int NT = 8;          // K=1024 / BK=128
  uint8_t* As = (uint8_t*)smem;  // 3 x 16384

  const int tid = threadIdx.x;
  const int wave = tid >> 6;  // 0..3
  const int lane = tid & 63;
  const int wm = wave >> 1;   // 0..1 : 64-row strip
  const int wn = wave & 1;    // 0..1 : 64-col strip
  const int rl = lane & 31;
  const int c0 = lane >> 5;
  const int m0 = bx * 128;
  const int n0 = by * 128;

  // ---- A staging (row-major, 16B chunk-swizzle within each 64B k-half:
  // chunk c of row r at slot c ^ ((r>>1)&3)).  Buffer = 16KB: two 8KB
  // k-halves, each 128 rows x 64B.  Per wave per step: 4 g2l16 (32 rows).
  const int sr = lane >> 2;  // 0..15
  const int sk = ((lane & 3) ^ ((sr >> 1) & 3)) * 16;
  const uint8_t* Ag = Arow + (size_t)(m0 + wave * 32 + sr) * 1024 + sk;
  const int lbase = wave * 2048;  // wave's 32 rows = 2KB within each half

#define A3_STAGE(buf, t)                                                     \
  do {                                                                       \
    _Pragma("unroll") for (int h_ = 0; h_ < 2; ++h_) {                       \
      g2l16(Ag + (size_t)(2 * (t) + h_) * 64,                                \
            As + (buf)*16384 + h_ * 8192 + lbase);                           \
      g2l16(Ag + 16 * 1024 + (size_t)(2 * (t) + h_) * 64,                    \
            As + (buf)*16384 + h_ * 8192 + lbase + 1024);                    \
    }                                                                        \
  } while (0)

  // ---- B fragment streams (2 per wave), double-buffer over steps;
  // each step consumes 2 chunks (k-halves) per stream.
  const uint8_t* Bg0 = BF + (size_t)(by * 4 + wn * 2 + 0) * 16 * 2048 + lane * 32;
  const uint8_t* Bg1 = BF + (size_t)(by * 4 + wn * 2 + 1) * 16 * 2048 + lane * 32;

  f32x16_t acc[2][2] = {};
  intx8_t bb[2][2][2];  // [par][khalf][j]

#define B_LOAD(par, t)                                                       \
  do {                                                                       \
    _Pragma("unroll") for (int h_ = 0; h_ < 2; ++h_) {                       \
      const size_t ck_ = (size_t)(2 * (t) + h_) * 2048;                      \
      *(intx4_t*)&bb[par][h_][0] = *(const intx4_t*)(Bg0 + ck_);             \
      *((intx4_t*)&bb[par][h_][0] + 1) = *(const intx4_t*)(Bg0 + ck_ + 16);  \
      *(intx4_t*)&bb[par][h_][1] = *(const intx4_t*)(Bg1 + ck_);             \
      *((intx4_t*)&bb[par][h_][1] + 1) = *(const intx4_t*)(Bg1 + ck_ + 16);  \
    }                                                                        \
  } while (0)

  // prologue: stage A(0),A(1) (4+4 ops); load B(0) (8 ops).
  // A(0) complete when <=12 outstanding (A(1) 4 + B(0) 8).
  A3_STAGE(0, 0);
  A3_STAGE(1, 1);
  B_LOAD(0, 0);
  asm volatile("s_waitcnt vmcnt(12)" ::: "memory");
  __builtin_amdgcn_s_barrier();
  asm volatile("" ::: "memory");

  const int w = (rl >> 1) & 3;
  const int sLo = ((2 * c0) ^ w) * 16;
  const int sHi = ((2 * c0 + 1) ^ w) * 16;

#pragma unroll
  for (int t = 0; t < NT; ++t) {
    if (t + 2 < NT) A3_STAGE((t + 2) % 3, t + 2);
    if (t + 1 < NT) B_LOAD((t + 1) & 1, t + 1);
    const uint8_t* Ab = As + (t % 3) * 16384;
#pragma unroll
    for (int kh = 0; kh < 2; ++kh) {
#pragma unroll
      for (int i = 0; i < 2; ++i) {
        const int ra = (wm * 64 + i * 32 + rl) * 64;
        intx8_t af;
        *(intx4_t*)&af = *(const intx4_t*)(Ab + kh * 8192 + ra + sLo);
        *((intx4_t*)&af + 1) = *(const intx4_t*)(Ab + kh * 8192 + ra + sHi);
#pragma unroll
        for (int j = 0; j < 2; ++j)
          acc[i][j] = __builtin_amdgcn_mfma_scale_f32_32x32x64_f8f6f4(
              af, bb[t & 1][kh][j], acc[i][j], 0, 0, 0, 0x79797979, 0,
              0x79797979);
      }
    }
    if (t < NT - 1) {
      // allow A(t+2) 4 + B(t+1) 8 outstanding; tail: only B(t+1) 8.
      if (t + 2 < NT)
        asm volatile("s_waitcnt vmcnt(12)" ::: "memory");
      else
        asm volatile("s_waitcnt vmcnt(8)" ::: "memory");
      __builtin_amdgcn_s_barrier();
      asm volatile("" ::: "memory");
    }
  }
#undef A3_STAGE
#undef B_LOAD

  // epilogue: C/D col = lane&31, row = (reg&3)+8*(reg>>2)+4*(lane>>5).
  // block's 128 cols are one full u-period -> out column 128+by.
  const int q = lane >> 5;
  float uu[2], b3[2];
#pragma unroll
  for (int j = 0; j < 2; ++j) {
    uu[j] = uvec[wn * 64 + j * 32 + rl];
    b3[j] = ab3[n0 + wn * 64 + j * 32 + rl];
  }
  const int ocol = 128 + by;
#pragma unroll
  for (int i = 0; i < 2; ++i) {
    float s16[16];
#pragma unroll
    for (int r = 0; r < 16; ++r)
      s16[r] = fast_tanh(acc[i][0][r] + b3[0]) * uu[0] +
               fast_tanh(acc[i][1][r] + b3[1]) * uu[1];
#pragma unroll
    for (int r = 0; r < 16; ++r) s16[r] = dpp_sum32(s16[r]);
    if (rl == 31) {  // lanes 31 and 63 hold the two q-half sums
      const int rowb = m0 + wm * 64 + i * 32 + 4 * q;
#pragma unroll
      for (int r = 0; r < 16; ++r)
        atomicAdd(&out[(size_t)(rowb + (r & 3) + 8 * (r >> 2)) * 256 + ocol],
                  s16[r]);
    }
  }
}

// ---------------------------------------------------------------------------
// transposes / cvt helpers
// ---------------------------------------------------------------------------
__device__ __forceinline__ void tcvt_body(char* smem, const float* in,
                                          bf16_t* out, int R, int C, int bx,
                                          int by) {
  float(*t)[33] = (float(*)[33])smem;  // 4224 B
  const int c0 = bx * 32;
  const int r0 = by * 32;
  const int tx = threadIdx.x & 31;
  const int ty = threadIdx.x >> 5;
#pragma unroll
  for (int k = 0; k < 4; ++k)
    t[ty + k * 8][tx] = in[(size_t)(r0 + ty + k * 8) * C + c0 + tx];
  __syncthreads();
#pragma unroll
  for (int k = 0; k < 4; ++k)
    out[(size_t)(c0 + ty + k * 8) * R + r0 + tx] = (bf16_t)t[tx][ty + k * 8];
}

// Aw3 (1024 x 16384) -> fp8 x64, FRAGMENT-MAJOR (Aw3T8F).
// 128x128 tile per block (1024 blocks), float4 reads, cvt_pk packing,
// u32-transposed LDS [128][33]; drain writes fragment chunks:
//   chunk ((cb*16)+kb)*2048, byte (khalf*32 + col%32)*32 + k%32.
__device__ __forceinline__ void aw3t_body(char* smem, const float* Aw3,
                                          uint8_t* Aw3T8F, int b) {
  uint32_t(*T)[33] = (uint32_t(*)[33])smem;  // 16896 B
  const int ct = b & 127;
  const int rt = b >> 7;
  const size_t c0 = (size_t)ct * 128;
  const int r0 = rt * 128;
  const int tx = threadIdx.x & 31;  // col-chunk (4 f32)
  const int g = threadIdx.x >> 5;   // 0..7 row-group
#pragma unroll
  for (int k = 0; k < 4; ++k) {
    const int rr = r0 + 4 * g + 32 * k;
    const float4 v0 = *(const float4*)(Aw3 + (size_t)(rr + 0) * 16384 + c0 + 4 * tx);
    const float4 v1 = *(const float4*)(Aw3 + (size_t)(rr + 1) * 16384 + c0 + 4 * tx);
    const float4 v2 = *(const float4*)(Aw3 + (size_t)(rr + 2) * 16384 + c0 + 4 * tx);
    const float4 v3 = *(const float4*)(Aw3 + (size_t)(rr + 3) * 16384 + c0 + 4 * tx);
    const int r4 = g + 8 * k;  // row/4 within tile (k-dim of output)
    T[4 * tx + 0][r4] = pk4_fp8(64.f * v0.x, 64.f * v1.x, 64.f * v2.x, 64.f * v3.x);
    T[4 * tx + 1][r4] = pk4_fp8(64.f * v0.y, 64.f * v1.y, 64.f * v2.y, 64.f * v3.y);
    T[4 * tx + 2][r4] = pk4_fp8(64.f * v0.z, 64.f * v1.z, 64.f * v2.z, 64.f * v3.z);
    T[4 * tx + 3][r4] = pk4_fp8(64.f * v0.w, 64.f * v1.w, 64.f * v2.w, 64.f * v3.w);
  }
  __syncthreads();
  // T[cc][tx] = 4 fp8 bytes: col = c0+cc, k = r0+4*tx .. +3
  const int kb = (rt << 1) + (tx >> 4);     // k-block (64)
  const int khalf = (tx >> 3) & 1;          // k-half (32)
  const int kin = (tx & 7) << 2;            // k%32 (4-aligned)
#pragma unroll
  for (int k2 = 0; k2 < 16; ++k2) {
    const int cc = g + 8 * k2;
    const int cb = (ct << 2) + (cc >> 5);
    const int cin = cc & 31;
    *(uint32_t*)(Aw3T8F + (size_t)(cb * 16 + kb) * 2048 +
                 (khalf * 32 + cin) * 32 + kin) = T[cc][tx];
  }
}

// one wave handles one row: pre2 = h.Hw2; w_j = s*Hw2_j*(1-h_j^2)
__device__ __forceinline__ void hgrad_row(int row, const bf16_t* h,
                                          const float* Hw2, const float* Hb2,
                                          bf16_t* wout) {
  const int lane = threadIdx.x & 63;
  float hv[10], wv[10];
  float pre2 = 0.f;
#pragma unroll
  for (int t = 0; t < 10; ++t) {
    const int j = lane + t * 64;
    hv[t] = (float)h[(size_t)row * 640 + j];
    wv[t] = Hw2[j];
    pre2 += hv[t] * wv[t];
  }
#pragma unroll
  for (int d = 1; d < 64; d <<= 1) pre2 += __shfl_xor(pre2, d, 64);
  const float y = fast_tanh(pre2 + Hb2[0]);
  const float s = 1.f - y * y;
#pragma unroll
  for (int t = 0; t < 10; ++t) {
    const int j = lane + t * 64;
    wout[(size_t)row * 640 + j] = (bf16_t)(s * wv[t] * (1.f - hv[t] * hv[t]));
  }
}

// ---------------------------------------------------------------------------
// L0: inp cvt (1024) + Hw1T (160) + Aw1T (64) + Aw2T (512) + Hw1_bf cvt (160)
//     + zero-out (1024) = 2944 blocks
// ---------------------------------------------------------------------------
__global__ __launch_bounds__(256) void launch0(
    const float* __restrict__ inp, bf16_t* __restrict__ inp_bf,
    const float* __restrict__ Hw1, bf16_t* __restrict__ Hw1T,
    bf16_t* __restrict__ Hw1_bf, const float* __restrict__ Aw1,
    bf16_t* __restrict__ Aw1T, const float* __restrict__ Aw2,
    bf16_t* __restrict__ Aw2T, float* __restrict__ out) {
  __shared__ __align__(16) char smem[4224];
  int b = blockIdx.x;
  if (b < 1024) {
    const int i = b * 256 + threadIdx.x;
    const float4 v = ((const float4*)inp)[i];
    bf16x4_t o = {(bf16_t)v.x, (bf16_t)v.y, (bf16_t)v.z, (bf16_t)v.w};
    ((bf16x4_t*)inp_bf)[i] = o;
  } else if (b < 1184) {
    int s = b - 1024;
    tcvt_body(smem, Hw1, Hw1T, 256, 640, s % 20, s / 20);
  } else if (b < 1248) {
    int s = b - 1184;
    tcvt_body(smem, Aw1, Aw1T, 128, 512, s % 16, s / 16);
  } else if (b < 1760) {
    int s = b - 1248;
    tcvt_body(smem, Aw2, Aw2T, 512, 1024, s % 32, s / 32);
  } else if (b < 1920) {
    const int i = (b - 1760) * 256 + threadIdx.x;
    const float4 v = ((const float4*)Hw1)[i];
    bf16x4_t o = {(bf16_t)v.x, (bf16_t)v.y, (bf16_t)v.z, (bf16_t)v.w};
    ((bf16x4_t*)Hw1_bf)[i] = o;
  } else {
    const int i = (b - 1920) * 256 + threadIdx.x;
    ((float4*)out)[i] = make_float4(0.f, 0.f, 0.f, 0.f);
  }
}

// ---------------------------------------------------------------------------
// L1: Hfwd 64^2 (640) + A1 64^2 (512) + Aw3T tiles [0,512) = 1664 blocks
// ---------------------------------------------------------------------------
__global__ __launch_bounds__(256) void launch1(
    const bf16_t* __restrict__ inp_bf, const bf16_t* __restrict__ Hw1T,
    const float* __restrict__ Hb1, bf16_t* __restrict__ h_bf,
    const bf16_t* __restrict__ Aw1T, const float* __restrict__ Ab1,
    bf16_t* __restrict__ h1_bf, const float* __restrict__ Aw3,
    uint8_t* __restrict__ Aw3T8F) {
  __shared__ __align__(16) char smem[SMEM_G64];
  const int b = blockIdx.x;
  if (b < 640) {
    gemm64_body<0>(smem, b % 64, b / 64, inp_bf, 256, Hw1T, 256, 256, Hb1,
                   h_bf, 640);
  } else if (b < 1152) {
    const int i = b - 640;
    gemm64_body<0>(smem, i % 64, i / 64, inp_bf, 256, Aw1T, 128, 128, Ab1,
                   h1_bf, 512);
  } else {
    aw3t_body(smem, Aw3, Aw3T8F, b - 1152);  // tiles 0..511
  }
}

// ---------------------------------------------------------------------------
// L2: A2->fp8 row-major (1024) + hgrad (1024) + Aw3T tiles [512,1024) = 2560
// ---------------------------------------------------------------------------
__global__ __launch_bounds__(256) void launch2(
    const bf16_t* __restrict__ h1_bf, const bf16_t* __restrict__ Aw2T,
    const float* __restrict__ Ab2, uint8_t* __restrict__ h2_f8,
    const bf16_t* __restrict__ h_bf, const float* __restrict__ Hw2,
    const float* __restrict__ Hb2, bf16_t* __restrict__ w_bf,
    const float* __restrict__ Aw3, uint8_t* __restrict__ Aw3T8F) {
  __shared__ __align__(16) char smem[SMEM_G64];
  const int b = blockIdx.x;
  if (b < 1024) {
    gemm64_body<3>(smem, b % 64, b / 64, h1_bf, 512, Aw2T, 512, 512, Ab2,
                   h2_f8, 1024);
  } else if (b < 2048) {
    const int row = (b - 1024) * 4 + (threadIdx.x >> 6);
    hgrad_row(row, h_bf, Hw2, Hb2, w_bf);
  } else {
    aw3t_body(smem, Aw3, Aw3T8F, 512 + (b - 2048));  // tiles 512..1023
  }
}

// ---------------------------------------------------------------------------
// L3 (256 threads): Hbwd 64^2 4-wave (256) + A3 hybrid 128x128 (4096) = 4352.
// __launch_bounds__(256,3): 3 blocks/CU = 12 waves (LDS 3x48KB = 144KB OK).
// A3 swizzle: hardware XCD = p%8; each XCD owns 16 contiguous by values
// (B working set 16 x 128KB = 2MB -> L2-resident), bx varies slowest.
// ---------------------------------------------------------------------------
__global__ __launch_bounds__(256, 3) void launch3(
    const bf16_t* __restrict__ w_bf, const bf16_t* __restrict__ Hw1_bf,
    float* __restrict__ out, const uint8_t* __restrict__ h2_f8,
    const uint8_t* __restrict__ Aw3T8F, const float* __restrict__ Ab3,
    const float* __restrict__ uvec) {
  __shared__ __align__(16) char smem[SMEM3_BYTES];
  const int b = blockIdx.x;
  if (b < 256) {
    gemm64_body<1>(smem, b % 64, b / 64, w_bf, 640, Hw1_bf, 640, 640, nullptr,
                   out, 256);
  } else {
    const int p = b - 256;                          // 0..4095; hw XCD = p % 8
    const int by = (p & 7) * 16 + ((p >> 3) & 15);  // 0..127
    const int bx = p >> 7;                          // 0..31
    a3_body(smem, bx, by, h2_f8, Aw3T8F, out, Ab3, uvec);
  }
}

// ---------------------------------------------------------------------------
extern "C" void kernel_launch(void* const* d_in, const int* in_sizes, int n_in,
                              void* d_out, int out_size, void* d_ws,
                              size_t ws_size, hipStream_t stream) {
  (void)in_sizes; (void)n_in; (void)out_size; (void)ws_size;
  const float* inp = (const float*)d_in[1];
  const float* Hw1 = (const float*)d_in[2];
  const float* Hb1 = (const float*)d_in[3];
  const float* Hw2 = (const float*)d_in[4];
  const float* Hb2 = (const float*)d_in[5];
  const float* Aw1 = (const float*)d_in[6];
  const float* Ab1 = (const float*)d_in[7];
  const float* Aw2 = (const float*)d_in[8];
  const float* Ab2 = (const float*)d_in[9];
  const float* Aw3 = (const float*)d_in[10];
  const float* Ab3 = (const float*)d_in[11];
  const float* u = (const float*)d_in[12];
  float* out = (float*)d_out;

  char* ws = (char*)d_ws;
  bf16_t* inp_bf = (bf16_t*)ws;    ws += (size_t)NROW * 256 * 2;
  bf16_t* Hw1_bf = (bf16_t*)ws;    ws += (size_t)256 * 640 * 2;
  bf16_t* Hw1T = (bf16_t*)ws;      ws += (size_t)640 * 256 * 2;
  bf16_t* Aw1T = (bf16_t*)ws;      ws += (size_t)512 * 128 * 2;
  bf16_t* Aw2T = (bf16_t*)ws;      ws += (size_t)1024 * 512 * 2;
  uint8_t* Aw3T8F = (uint8_t*)ws;  ws += (size_t)16384 * 1024;
  bf16_t* h_bf = (bf16_t*)ws;      ws += (size_t)NROW * 640 * 2;
  bf16_t* w_bf = (bf16_t*)ws;      ws += (size_t)NROW * 640 * 2;
  bf16_t* h1_bf = (bf16_t*)ws;     ws += (size_t)NROW * 512 * 2;
  uint8_t* h2_f8 = (uint8_t*)ws;   ws += (size_t)NROW * 1024;

  launch0<<<2944, 256, 0, stream>>>(inp, inp_bf, Hw1, Hw1T, Hw1_bf, Aw1, Aw1T,
                                    Aw2, Aw2T, out);
  launch1<<<1664, 256, 0, stream>>>(inp_bf, Hw1T, Hb1, h_bf, Aw1T, Ab1, h1_bf,
                                    Aw3, Aw3T8F);
  launch2<<<2560, 256, 0, stream>>>(h1_bf, Aw2T, Ab2, h2_f8, h_bf, Hw2, Hb2,
                                    w_bf, Aw3, Aw3T8F);
  launch3<<<4352, 256, 0, stream>>>(w_bf, Hw1_bf, out, h2_f8, Aw3T8F, Ab3, u);
}

// Round 14
// 225.991 us; speedup vs baseline: 1.1710x; 1.0085x over previous
//
#include <hip/hip_runtime.h>
#include <hip/hip_bf16.h>
#include <cstdint>

// ---------------------------------------------------------------------------
// Hamilton_V5  R23 = R22 with A3 pushed to 16 waves/CU:
//  - A-LDS triple -> DOUBLE buffer (2 x 16KB = 32KB): T3-minimum pattern --
//    STAGE(t+1) issued at step start, single vmcnt(0)+barrier per step
//    (stage has the whole ~500cy step to land).
//  - B loads just-in-time per k-half into 2 named intx8 regs (data-dep
//    waits): B reg footprint 64 -> 16. Total demand ~115 regs.
//  - __launch_bounds__(256,4) caps at 128 regs -> 4 waves/SIMD; LDS 32KB
//    -> 4 blocks/CU -> 16 waves (50%), vs R22's 12 (29.6% measured).
//    Doubled TLP hides the B-stream L2 latency that JIT loading exposes.
//  - Everything else byte-identical to R22.
// ---------------------------------------------------------------------------

typedef __bf16 bf16_t;
typedef __bf16 bf16x4_t __attribute__((ext_vector_type(4)));
typedef __bf16 bf16x8_t __attribute__((ext_vector_type(8)));
typedef float f32x4_t __attribute__((ext_vector_type(4)));
typedef float f32x16_t __attribute__((ext_vector_type(16)));
typedef int intx4_t __attribute__((ext_vector_type(4)));
typedef int intx8_t __attribute__((ext_vector_type(8)));

#define DIMD 128
#define NROW 4096
#define SMEM_G64 24576     // gemm64 3-buf (3*4096*2) ; aw3t 16896 fits
#define SMEM3_BYTES 32768  // a3: 2 x 16384 (A tiles); hbwd uses 24576

// branchless tanh: t=2^(2x*log2e); tanh=1-2/(t+1).
__device__ __forceinline__ float fast_tanh(float x) {
  float t = __builtin_amdgcn_exp2f(x * 2.8853900817779268f);
  return 1.f - 2.f * __builtin_amdgcn_rcpf(t + 1.f);
}

// f32 -> fp8 e4m3 (OCP), RNE+sat via HW cvt
__device__ __forceinline__ uint8_t to_fp8(float x) {
  return (uint8_t)(__builtin_amdgcn_cvt_pk_fp8_f32(x, x, 0, false) & 0xff);
}

// pack 4 f32 -> 4 fp8 bytes (byte0=a .. byte3=d) via 2 HW cvt_pk
__device__ __forceinline__ uint32_t pk4_fp8(float a, float b, float c,
                                            float d) {
  uint32_t lo = (uint32_t)__builtin_amdgcn_cvt_pk_fp8_f32(a, b, 0, false);
  return (uint32_t)__builtin_amdgcn_cvt_pk_fp8_f32(c, d, lo, true);
}

// async global->LDS, 16B per lane; LDS dest = wave-uniform base + lane*16
__device__ __forceinline__ void g2l16(const void* gp, void* lp) {
  __builtin_amdgcn_global_load_lds(
      reinterpret_cast<__attribute__((address_space(1))) void*>(
          reinterpret_cast<uintptr_t>(gp)),
      reinterpret_cast<__attribute__((address_space(3))) void*>(
          reinterpret_cast<uintptr_t>(lp)),
      16, 0, 0);
}

// DPP accumulating add (VALU pipe -- no LDS). bound_ctrl=1 => 0-fill.
template <int CTRL>
__device__ __forceinline__ float dpp_addf(float v) {
  return v + __int_as_float(__builtin_amdgcn_update_dpp(
                 0, __float_as_int(v), CTRL, 0xf, 0xf, true));
}
// sum over each 32-lane half; result in lane 31 (half 0) / lane 63 (half 1).
__device__ __forceinline__ float dpp_sum32(float v) {
  v = dpp_addf<0x111>(v);  // row_shr:1
  v = dpp_addf<0x112>(v);  // row_shr:2
  v = dpp_addf<0x114>(v);  // row_shr:4
  v = dpp_addf<0x118>(v);  // row_shr:8  -> lane15/31/47/63 = row sums
  v = dpp_addf<0x142>(v);  // row_bcast15 -> lane31/63 = 32-lane sums
  return v;
}

// ---------------------------------------------------------------------------
// bf16 GEMM, 64x64 tile, BK=32, 4 waves 2x2 (each 32x32 = 2x2 mfma 16x16x32).
// Triple-buffered LDS, depth-2 prefetch, counted vmcnt(2) per step.
// EPI 0: bf16 tanh(C+b); EPI 1: dx store / dv atomicAdd(-C);
// EPI 3: fp8 x64 row-major.  (256-thread launches.)
// ---------------------------------------------------------------------------
template <int EPI>
__device__ __forceinline__ void gemm64_body(char* smem, int bx, int by,
                                            const bf16_t* A, int lda,
                                            const bf16_t* B, int ldb, int K,
                                            const float* bias, void* outp,
                                            int ldo) {
  constexpr int BK = 32;
  bf16_t* As = (bf16_t*)smem;   // 3 x 64*32
  bf16_t* Bs = As + 3 * 2048;   // 3 x 64*32
  const int NT = K / BK;

  const int m0 = bx * 64;
  const int n0 = by * 64;
  const int tid = threadIdx.x;
  const int wave = tid >> 6;
  const int lane = tid & 63;
  const int wm = wave >> 1;
  const int wn = wave & 1;

  const int sr = lane >> 2;
  const int sk = (((lane & 3) ^ ((sr >> 1) & 3)) * 8);
  const int fr = lane & 15;
  const int fk = (((lane >> 4) ^ ((fr >> 1) & 3)) * 8);
  const int rb = wave * 16;  // each wave stages 16 rows of A and B

  const bf16_t* Ag = A + (size_t)(m0 + rb + sr) * lda + sk;
  const bf16_t* Bg = B + (size_t)(n0 + rb + sr) * ldb + sk;

#define G64_STAGE(buf, k0)                              \
  do {                                                  \
    g2l16(Ag + (k0), As + (buf) * 2048 + rb * BK);      \
    g2l16(Bg + (k0), Bs + (buf) * 2048 + rb * BK);      \
  } while (0)

  f32x4_t acc[2][2] = {};

  G64_STAGE(0, 0);
  G64_STAGE(1, BK);
  asm volatile("s_waitcnt vmcnt(2)" ::: "memory");
  __builtin_amdgcn_s_barrier();
  asm volatile("" ::: "memory");

  for (int t = 0; t < NT; ++t) {
    if (t + 2 < NT) G64_STAGE((t + 2) % 3, (t + 2) * BK);
    const bf16_t* Ab = As + (t % 3) * 2048;
    const bf16_t* Bb = Bs + (t % 3) * 2048;

    bf16x8_t af[2], bb[2];
#pragma unroll
    for (int u = 0; u < 2; ++u) {
      af[u] = *(const bf16x8_t*)(Ab + (wm * 32 + u * 16 + fr) * BK + fk);
      bb[u] = *(const bf16x8_t*)(Bb + (wn * 32 + u * 16 + fr) * BK + fk);
    }
#pragma unroll
    for (int i = 0; i < 2; ++i)
#pragma unroll
      for (int j = 0; j < 2; ++j)
        acc[i][j] = __builtin_amdgcn_mfma_f32_16x16x32_bf16(af[i], bb[j],
                                                            acc[i][j], 0, 0, 0);
    if (t < NT - 1) {
      if (t + 2 < NT)
        asm volatile("s_waitcnt vmcnt(2)" ::: "memory");
      else
        asm volatile("s_waitcnt vmcnt(0)" ::: "memory");
      __builtin_amdgcn_s_barrier();
      asm volatile("" ::: "memory");
    }
  }
#undef G64_STAGE

  // C/D layout (m89): col = lane&15, row = (lane>>4)*4 + reg
#pragma unroll
  for (int i = 0; i < 2; ++i) {
    const int row = m0 + wm * 32 + i * 16 + (lane >> 4) * 4;
#pragma unroll
    for (int j = 0; j < 2; ++j) {
      const int col = n0 + wn * 32 + j * 16 + fr;
      if constexpr (EPI == 0) {
        bf16_t* O = (bf16_t*)outp;
        const float b = bias[col];
#pragma unroll
        for (int r = 0; r < 4; ++r)
          O[(size_t)(row + r) * ldo + col] = (bf16_t)fast_tanh(acc[i][j][r] + b);
      } else if constexpr (EPI == 1) {
        float* O = (float*)outp;
        const bool dx = (n0 < DIMD);
#pragma unroll
        for (int r = 0; r < 4; ++r) {
          const size_t idx = (size_t)(row + r) * ldo + col;
          if (dx) O[idx] = acc[i][j][r];
          else atomicAdd(&O[idx], -acc[i][j][r]);  // dv_H shares with dvA
        }
      } else {  // EPI 3: fp8 x64 row-major
        uint8_t* O = (uint8_t*)outp;
        const float b = bias[col];
#pragma unroll
        for (int r = 0; r < 4; ++r)
          O[(size_t)(row + r) * ldo + col] =
              to_fp8(64.f * fast_tanh(acc[i][j][r] + b));
      }
    }
  }
}

// ---------------------------------------------------------------------------
// A3 fused GEMM, MX-fp8, R23: 256 threads / 4 waves, 128x128, BK=128.
// Wave grid 2x2: each wave 64x64 via 2x2 mfma 32x32x64 (acc[2][2] = 64 AGPR).
// A (row-major h2_f8): LDS DOUBLE-buffer (2x16KB), stage(t+1) at step start,
//   one vmcnt(0)+barrier per step (T3-minimum).
// B (fragment Aw3T8F): just-in-time per k-half into 2 intx8 (data-dep waits).
// 8 K-steps, 8 barriers.  16 waves/CU (4 blocks x 4 waves).
// ---------------------------------------------------------------------------
__device__ __forceinline__ void a3_body(char* smem, int bx, int by,
                                        const uint8_t* Arow,
                                        const uint8_t* BF, float* out,
                                        const float* ab3, const float* uvec) {
  constexpr int NT = 8;          // K=1024 / BK=128
  uint8_t* As = (uint8_t*)smem;  // 2 x 16384

  const int tid = threadIdx.x;
  const int wave = tid >> 6;  // 0..3
  const int lane = tid & 63;
  const int wm = wave >> 1;   // 0..1 : 64-row strip
  const int wn = wave & 1;    // 0..1 : 64-col strip
  const int rl = lane & 31;
  const int c0 = lane >> 5;
  const int m0 = bx * 128;
  const int n0 = by * 128;

  // ---- A staging (row-major, 16B chunk-swizzle within each 64B k-half:
  // chunk c of row r at slot c ^ ((r>>1)&3)).  Buffer = 16KB: two 8KB
  // k-halves, each 128 rows x 64B.  Per wave per step: 4 g2l16 (32 rows).
  const int sr = lane >> 2;  // 0..15
  const int sk = ((lane & 3) ^ ((sr >> 1) & 3)) * 16;
  const uint8_t* Ag = Arow + (size_t)(m0 + wave * 32 + sr) * 1024 + sk;
  const int lbase = wave * 2048;  // wave's 32 rows = 2KB within each half

#define A3_STAGE(buf, t)                                                     \
  do {                                                                       \
    _Pragma("unroll") for (int h_ = 0; h_ < 2; ++h_) {                       \
      g2l16(Ag + (size_t)(2 * (t) + h_) * 64,                                \
            As + (buf)*16384 + h_ * 8192 + lbase);                           \
      g2l16(Ag + 16 * 1024 + (size_t)(2 * (t) + h_) * 64,                    \
            As + (buf)*16384 + h_ * 8192 + lbase + 1024);                    \
    }                                                                        \
  } while (0)

  // ---- B fragment streams (2 per wave), loaded just-in-time per k-half.
  const uint8_t* Bg0 = BF + (size_t)(by * 4 + wn * 2 + 0) * 16 * 2048 + lane * 32;
  const uint8_t* Bg1 = BF + (size_t)(by * 4 + wn * 2 + 1) * 16 * 2048 + lane * 32;

  f32x16_t acc[2][2] = {};

  // prologue: stage A(0); drain; barrier.
  A3_STAGE(0, 0);
  asm volatile("s_waitcnt vmcnt(0)" ::: "memory");
  __builtin_amdgcn_s_barrier();
  asm volatile("" ::: "memory");

  const int w = (rl >> 1) & 3;
  const int sLo = ((2 * c0) ^ w) * 16;
  const int sHi = ((2 * c0 + 1) ^ w) * 16;

#pragma unroll
  for (int t = 0; t < NT; ++t) {
    if (t + 1 < NT) A3_STAGE((t + 1) & 1, t + 1);
    const uint8_t* Ab = As + (t & 1) * 16384;
#pragma unroll
    for (int kh = 0; kh < 2; ++kh) {
      // JIT B chunk (2t+kh) for both streams (4 x dwordx4)
      const size_t ck = (size_t)(2 * t + kh) * 2048;
      intx8_t b0, b1;
      *(intx4_t*)&b0 = *(const intx4_t*)(Bg0 + ck);
      *((intx4_t*)&b0 + 1) = *(const intx4_t*)(Bg0 + ck + 16);
      *(intx4_t*)&b1 = *(const intx4_t*)(Bg1 + ck);
      *((intx4_t*)&b1 + 1) = *(const intx4_t*)(Bg1 + ck + 16);
#pragma unroll
      for (int i = 0; i < 2; ++i) {
        const int ra = (wm * 64 + i * 32 + rl) * 64;
        intx8_t af;
        *(intx4_t*)&af = *(const intx4_t*)(Ab + kh * 8192 + ra + sLo);
        *((intx4_t*)&af + 1) = *(const intx4_t*)(Ab + kh * 8192 + ra + sHi);
        acc[i][0] = __builtin_amdgcn_mfma_scale_f32_32x32x64_f8f6f4(
            af, b0, acc[i][0], 0, 0, 0, 0x79797979, 0, 0x79797979);
        acc[i][1] = __builtin_amdgcn_mfma_scale_f32_32x32x64_f8f6f4(
            af, b1, acc[i][1], 0, 0, 0, 0x79797979, 0, 0x79797979);
      }
    }
    if (t < NT - 1) {
      // A(t+1) must be resident before the next step reads buf (t+1)&1.
      // B loads are already retired via data-dep waits -> this drains A only.
      asm volatile("s_waitcnt vmcnt(0)" ::: "memory");
      __builtin_amdgcn_s_barrier();
      asm volatile("" ::: "memory");
    }
  }
#undef A3_STAGE

  // epilogue: C/D col = lane&31, row = (reg&3)+8*(reg>>2)+4*(lane>>5).
  // block's 128 cols are one full u-period -> out column 128+by.
  const int q = lane >> 5;
  float uu[2], b3[2];
#pragma unroll
  for (int j = 0; j < 2; ++j) {
    uu[j] = uvec[wn * 64 + j * 32 + rl];
    b3[j] = ab3[n0 + wn * 64 + j * 32 + rl];
  }
  const int ocol = 128 + by;
#pragma unroll
  for (int i = 0; i < 2; ++i) {
    float s16[16];
#pragma unroll
    for (int r = 0; r < 16; ++r)
      s16[r] = fast_tanh(acc[i][0][r] + b3[0]) * uu[0] +
               fast_tanh(acc[i][1][r] + b3[1]) * uu[1];
#pragma unroll
    for (int r = 0; r < 16; ++r) s16[r] = dpp_sum32(s16[r]);
    if (rl == 31) {  // lanes 31 and 63 hold the two q-half sums
      const int rowb = m0 + wm * 64 + i * 32 + 4 * q;
#pragma unroll
      for (int r = 0; r < 16; ++r)
        atomicAdd(&out[(size_t)(rowb + (r & 3) + 8 * (r >> 2)) * 256 + ocol],
                  s16[r]);
    }
  }
}

// ---------------------------------------------------------------------------
// transposes / cvt helpers
// ---------------------------------------------------------------------------
__device__ __forceinline__ void tcvt_body(char* smem, const float* in,
                                          bf16_t* out, int R, int C, int bx,
                                          int by) {
  float(*t)[33] = (float(*)[33])smem;  // 4224 B
  const int c0 = bx * 32;
  const int r0 = by * 32;
  const int tx = threadIdx.x & 31;
  const int ty = threadIdx.x >> 5;
#pragma unroll
  for (int k = 0; k < 4; ++k)
    t[ty + k * 8][tx] = in[(size_t)(r0 + ty + k * 8) * C + c0 + tx];
  __syncthreads();
#pragma unroll
  for (int k = 0; k < 4; ++k)
    out[(size_t)(c0 + ty + k * 8) * R + r0 + tx] = (bf16_t)t[tx][ty + k * 8];
}

// Aw3 (1024 x 16384) -> fp8 x64, FRAGMENT-MAJOR (Aw3T8F).
// 128x128 tile per block (1024 blocks), float4 reads, cvt_pk packing,
// u32-transposed LDS [128][33]; drain writes fragment chunks:
//   chunk ((cb*16)+kb)*2048, byte (khalf*32 + col%32)*32 + k%32.
__device__ __forceinline__ void aw3t_body(char* smem, const float* Aw3,
                                          uint8_t* Aw3T8F, int b) {
  uint32_t(*T)[33] = (uint32_t(*)[33])smem;  // 16896 B
  const int ct = b & 127;
  const int rt = b >> 7;
  const size_t c0 = (size_t)ct * 128;
  const int r0 = rt * 128;
  const int tx = threadIdx.x & 31;  // col-chunk (4 f32)
  const int g = threadIdx.x >> 5;   // 0..7 row-group
#pragma unroll
  for (int k = 0; k < 4; ++k) {
    const int rr = r0 + 4 * g + 32 * k;
    const float4 v0 = *(const float4*)(Aw3 + (size_t)(rr + 0) * 16384 + c0 + 4 * tx);
    const float4 v1 = *(const float4*)(Aw3 + (size_t)(rr + 1) * 16384 + c0 + 4 * tx);
    const float4 v2 = *(const float4*)(Aw3 + (size_t)(rr + 2) * 16384 + c0 + 4 * tx);
    const float4 v3 = *(const float4*)(Aw3 + (size_t)(rr + 3) * 16384 + c0 + 4 * tx);
    const int r4 = g + 8 * k;  // row/4 within tile (k-dim of output)
    T[4 * tx + 0][r4] = pk4_fp8(64.f * v0.x, 64.f * v1.x, 64.f * v2.x, 64.f * v3.x);
    T[4 * tx + 1][r4] = pk4_fp8(64.f * v0.y, 64.f * v1.y, 64.f * v2.y, 64.f * v3.y);
    T[4 * tx + 2][r4] = pk4_fp8(64.f * v0.z, 64.f * v1.z, 64.f * v2.z, 64.f * v3.z);
    T[4 * tx + 3][r4] = pk4_fp8(64.f * v0.w, 64.f * v1.w, 64.f * v2.w, 64.f * v3.w);
  }
  __syncthreads();
  // T[cc][tx] = 4 fp8 bytes: col = c0+cc, k = r0+4*tx .. +3
  const int kb = (rt << 1) + (tx >> 4);     // k-block (64)
  const int khalf = (tx >> 3) & 1;          // k-half (32)
  const int kin = (tx & 7) << 2;            // k%32 (4-aligned)
#pragma unroll
  for (int k2 = 0; k2 < 16; ++k2) {
    const int cc = g + 8 * k2;
    const int cb = (ct << 2) + (cc >> 5);
    const int cin = cc & 31;
    *(uint32_t*)(Aw3T8F + (size_t)(cb * 16 + kb) * 2048 +
                 (khalf * 32 + cin) * 32 + kin) = T[cc][tx];
  }
}

// one wave handles one row: pre2 = h.Hw2; w_j = s*Hw2_j*(1-h_j^2)
__device__ __forceinline__ void hgrad_row(int row, const bf16_t* h,
                                          const float* Hw2, const float* Hb2,
                                          bf16_t* wout) {
  const int lane = threadIdx.x & 63;
  float hv[10], wv[10];
  float pre2 = 0.f;
#pragma unroll
  for (int t = 0; t < 10; ++t) {
    const int j = lane + t * 64;
    hv[t] = (float)h[(size_t)row * 640 + j];
    wv[t] = Hw2[j];
    pre2 += hv[t] * wv[t];
  }
#pragma unroll
  for (int d = 1; d < 64; d <<= 1) pre2 += __shfl_xor(pre2, d, 64);
  const float y = fast_tanh(pre2 + Hb2[0]);
  const float s = 1.f - y * y;
#pragma unroll
  for (int t = 0; t < 10; ++t) {
    const int j = lane + t * 64;
    wout[(size_t)row * 640 + j] = (bf16_t)(s * wv[t] * (1.f - hv[t] * hv[t]));
  }
}

// ---------------------------------------------------------------------------
// L0: inp cvt (1024) + Hw1T (160) + Aw1T (64) + Aw2T (512) + Hw1_bf cvt (160)
//     + zero-out (1024) = 2944 blocks
// ---------------------------------------------------------------------------
__global__ __launch_bounds__(256) void launch0(
    const float* __restrict__ inp, bf16_t* __restrict__ inp_bf,
    const float* __restrict__ Hw1, bf16_t* __restrict__ Hw1T,
    bf16_t* __restrict__ Hw1_bf, const float* __restrict__ Aw1,
    bf16_t* __restrict__ Aw1T, const float* __restrict__ Aw2,
    bf16_t* __restrict__ Aw2T, float* __restrict__ out) {
  __shared__ __align__(16) char smem[4224];
  int b = blockIdx.x;
  if (b < 1024) {
    const int i = b * 256 + threadIdx.x;
    const float4 v = ((const float4*)inp)[i];
    bf16x4_t o = {(bf16_t)v.x, (bf16_t)v.y, (bf16_t)v.z, (bf16_t)v.w};
    ((bf16x4_t*)inp_bf)[i] = o;
  } else if (b < 1184) {
    int s = b - 1024;
    tcvt_body(smem, Hw1, Hw1T, 256, 640, s % 20, s / 20);
  } else if (b < 1248) {
    int s = b - 1184;
    tcvt_body(smem, Aw1, Aw1T, 128, 512, s % 16, s / 16);
  } else if (b < 1760) {
    int s = b - 1248;
    tcvt_body(smem, Aw2, Aw2T, 512, 1024, s % 32, s / 32);
  } else if (b < 1920) {
    const int i = (b - 1760) * 256 + threadIdx.x;
    const float4 v = ((const float4*)Hw1)[i];
    bf16x4_t o = {(bf16_t)v.x, (bf16_t)v.y, (bf16_t)v.z, (bf16_t)v.w};
    ((bf16x4_t*)Hw1_bf)[i] = o;
  } else {
    const int i = (b - 1920) * 256 + threadIdx.x;
    ((float4*)out)[i] = make_float4(0.f, 0.f, 0.f, 0.f);
  }
}

// ---------------------------------------------------------------------------
// L1: Hfwd 64^2 (640) + A1 64^2 (512) + Aw3T tiles [0,512) = 1664 blocks
// ---------------------------------------------------------------------------
__global__ __launch_bounds__(256) void launch1(
    const bf16_t* __restrict__ inp_bf, const bf16_t* __restrict__ Hw1T,
    const float* __restrict__ Hb1, bf16_t* __restrict__ h_bf,
    const bf16_t* __restrict__ Aw1T, const float* __restrict__ Ab1,
    bf16_t* __restrict__ h1_bf, const float* __restrict__ Aw3,
    uint8_t* __restrict__ Aw3T8F) {
  __shared__ __align__(16) char smem[SMEM_G64];
  const int b = blockIdx.x;
  if (b < 640) {
    gemm64_body<0>(smem, b % 64, b / 64, inp_bf, 256, Hw1T, 256, 256, Hb1,
                   h_bf, 640);
  } else if (b < 1152) {
    const int i = b - 640;
    gemm64_body<0>(smem, i % 64, i / 64, inp_bf, 256, Aw1T, 128, 128, Ab1,
                   h1_bf, 512);
  } else {
    aw3t_body(smem, Aw3, Aw3T8F, b - 1152);  // tiles 0..511
  }
}

// ---------------------------------------------------------------------------
// L2: A2->fp8 row-major (1024) + hgrad (1024) + Aw3T tiles [512,1024) = 2560
// ---------------------------------------------------------------------------
__global__ __launch_bounds__(256) void launch2(
    const bf16_t* __restrict__ h1_bf, const bf16_t* __restrict__ Aw2T,
    const float* __restrict__ Ab2, uint8_t* __restrict__ h2_f8,
    const bf16_t* __restrict__ h_bf, const float* __restrict__ Hw2,
    const float* __restrict__ Hb2, bf16_t* __restrict__ w_bf,
    const float* __restrict__ Aw3, uint8_t* __restrict__ Aw3T8F) {
  __shared__ __align__(16) char smem[SMEM_G64];
  const int b = blockIdx.x;
  if (b < 1024) {
    gemm64_body<3>(smem, b % 64, b / 64, h1_bf, 512, Aw2T, 512, 512, Ab2,
                   h2_f8, 1024);
  } else if (b < 2048) {
    const int row = (b - 1024) * 4 + (threadIdx.x >> 6);
    hgrad_row(row, h_bf, Hw2, Hb2, w_bf);
  } else {
    aw3t_body(smem, Aw3, Aw3T8F, 512 + (b - 2048));  // tiles 512..1023
  }
}

// ---------------------------------------------------------------------------
// L3 (256 threads): Hbwd 64^2 4-wave (256) + A3 hybrid 128x128 (4096) = 4352.
// __launch_bounds__(256,4): 4 waves/SIMD cap (128 regs); LDS 32KB -> 4
// blocks/CU = 16 waves.
// A3 swizzle: hardware XCD = p%8; each XCD owns 16 contiguous by values
// (B working set 16 x 128KB = 2MB -> L2-resident), bx varies slowest.
// ---------------------------------------------------------------------------
__global__ __launch_bounds__(256, 4) void launch3(
    const bf16_t* __restrict__ w_bf, const bf16_t* __restrict__ Hw1_bf,
    float* __restrict__ out, const uint8_t* __restrict__ h2_f8,
    const uint8_t* __restrict__ Aw3T8F, const float* __restrict__ Ab3,
    const float* __restrict__ uvec) {
  __shared__ __align__(16) char smem[SMEM3_BYTES];
  const int b = blockIdx.x;
  if (b < 256) {
    gemm64_body<1>(smem, b % 64, b / 64, w_bf, 640, Hw1_bf, 640, 640, nullptr,
                   out, 256);
  } else {
    const int p = b - 256;                          // 0..4095; hw XCD = p % 8
    const int by = (p & 7) * 16 + ((p >> 3) & 15);  // 0..127
    const int bx = p >> 7;                          // 0..31
    a3_body(smem, bx, by, h2_f8, Aw3T8F, out, Ab3, uvec);
  }
}

// ---------------------------------------------------------------------------
extern "C" void kernel_launch(void* const* d_in, const int* in_sizes, int n_in,
                              void* d_out, int out_size, void* d_ws,
                              size_t ws_size, hipStream_t stream) {
  (void)in_sizes; (void)n_in; (void)out_size; (void)ws_size;
  const float* inp = (const float*)d_in[1];
  const float* Hw1 = (const float*)d_in[2];
  const float* Hb1 = (const float*)d_in[3];
  const float* Hw2 = (const float*)d_in[4];
  const float* Hb2 = (const float*)d_in[5];
  const float* Aw1 = (const float*)d_in[6];
  const float* Ab1 = (const float*)d_in[7];
  const float* Aw2 = (const float*)d_in[8];
  const float* Ab2 = (const float*)d_in[9];
  const float* Aw3 = (const float*)d_in[10];
  const float* Ab3 = (const float*)d_in[11];
  const float* u = (const float*)d_in[12];
  float* out = (float*)d_out;

  char* ws = (char*)d_ws;
  bf16_t* inp_bf = (bf16_t*)ws;    ws += (size_t)NROW * 256 * 2;
  bf16_t* Hw1_bf = (bf16_t*)ws;    ws += (size_t)256 * 640 * 2;
  bf16_t* Hw1T = (bf16_t*)ws;      ws += (size_t)640 * 256 * 2;
  bf16_t* Aw1T = (bf16_t*)ws;      ws += (size_t)512 * 128 * 2;
  bf16_t* Aw2T = (bf16_t*)ws;      ws += (size_t)1024 * 512 * 2;
  uint8_t* Aw3T8F = (uint8_t*)ws;  ws += (size_t)16384 * 1024;
  bf16_t* h_bf = (bf16_t*)ws;      ws += (size_t)NROW * 640 * 2;
  bf16_t* w_bf = (bf16_t*)ws;      ws += (size_t)NROW * 640 * 2;
  bf16_t* h1_bf = (bf16_t*)ws;     ws += (size_t)NROW * 512 * 2;
  uint8_t* h2_f8 = (uint8_t*)ws;   ws += (size_t)NROW * 1024;

  launch0<<<2944, 256, 0, stream>>>(inp, inp_bf, Hw1, Hw1T, Hw1_bf, Aw1, Aw1T,
                                    Aw2, Aw2T, out);
  launch1<<<1664, 256, 0, stream>>>(inp_bf, Hw1T, Hb1, h_bf, Aw1T, Ab1, h1_bf,
                                    Aw3, Aw3T8F);
  launch2<<<2560, 256, 0, stream>>>(h1_bf, Aw2T, Ab2, h2_f8, h_bf, Hw2, Hb2,
                                    w_bf, Aw3, Aw3T8F);
  launch3<<<4352, 256, 0, stream>>>(w_bf, Hw1_bf, out, h2_f8, Aw3T8F, Ab3, u);
}